// Round 13
// baseline (323.173 us; speedup 1.0000x reference)
//
#include <hip/hip_runtime.h>
#include <hip/hip_bf16.h>
#include <math.h>

// ---------------------------------------------------------------------------
// CLSNet forward. B=8, C=128, H=W=128, Horg=Worg=512, NC=6, KP=8, NPROTO=48,
// PH=PW=4 (patches 32x32), 128 patches, 768 center rows.
// Outputs: pred[8,6,512,512] | proto_expand[8,48,128] | p2c[8,48,128,128] |
// distance_l2[8,48,16384] | proto_new[48,128]
// gt arrives as int32.
// R12 post-mortem: kernE v7 (prot from global) = +24 µs regression — 2nd
// confirmation that global-in-dep-chain loses to LDS at 2 blocks/CU.
// kernE REVERTED to v5.1 verbatim (R7/R11-measured ~51 µs). LDS-instr-count
// model retired; v5.1 is a latency-structure local optimum.
// R13 delta (ONE change, different kernels): centersT layout flipped
// [c][768] -> [row][128]. kernA2 writes become 2 coalesced 256B stores per
// row (was 768-stride scatter); kernD reads become one contiguous line per
// i, 8 in flight (was per-lane 3KB-stride float4 scatter = 64 reqs/instr).
// Scan order & semantics unchanged.
// ---------------------------------------------------------------------------

#define E_M1 1.71828182845904523536f   // e - 1
#define INV_SQRT2 0.70710678118654752440f

typedef float v2f __attribute__((ext_vector_type(2)));

__device__ __forceinline__ float gelu_exact(float x) {
    return 0.5f * x * (1.f + erff(x * INV_SQRT2));
}
__device__ __forceinline__ v2f splat2(float x) { v2f r; r.x = x; r.y = x; return r; }

// async 16-B global -> LDS DMA (gfx950). LDS dest must be wave-uniform
// base + lane*16 at the issuing instruction — caller guarantees linearity.
__device__ __forceinline__ void gload16(const float* g, float* l) {
    __builtin_amdgcn_global_load_lds(
        (const __attribute__((address_space(1))) void*)g,
        (__attribute__((address_space(3))) void*)l, 16, 0, 0);
}

// ---------------------------------------------------------------------------
// kernA1 v4: fused mask-gen + per-(patch,quarter) segmented channel sums.
// 512 blocks x 512 threads. Phase 0 (t<256): scrambled one-hot 6-bit mask
// for the block's 8x32 pixel region (verbatim kern0b formula) -> LDS msk +
// global maskb (consumed by kernA2). Phase 1: gather, sub = t>>7 handles
// 2 of the 8 rows; LDS combine. part layout: part[pidx][7][128].
// ---------------------------------------------------------------------------
__global__ __launch_bounds__(512) void kernA1(
    const float* __restrict__ feats, const int* __restrict__ gt,
    unsigned char* __restrict__ maskb, float* __restrict__ part)
{
    __shared__ float accs[3][7][128];
    __shared__ unsigned char msk[256];          // [8 rows][32 cols]
    const int pidx = blockIdx.x;
    const int patch = pidx >> 2, q = pidx & 3;
    const int b = patch >> 4, pp = patch & 15, ihh = pp >> 2, iww = pp & 3;
    const int c = threadIdx.x & 127, sub = threadIdx.x >> 7;
    const int rowb = ihh * 32 + q * 8, colb = iww * 32;

    // ---- phase 0: mask bytes for this block's 256 pixels ----
    if (threadIdx.x < 256) {
        const int prow = threadIdx.x >> 5, pcol = threadIdx.x & 31;
        const int P = (rowb + prow) * 128 + colb + pcol;
        const int* gb = gt + b * 262144;
        unsigned int m = 0;
        #pragma unroll
        for (int cc = 0; cc < 6; ++cc) {
            int pos = cc * 16384 + P;
            int hp = pos / 768;
            int rem = pos - hp * 768;
            int wp = rem / 6;
            int kp = rem - wp * 6;
            int g = gb[(4 * hp) * 512 + 4 * wp];
            int lab = (g == 6) ? 0 : g;
            if (lab == kp) m |= (1u << cc);
        }
        msk[threadIdx.x] = (unsigned char)m;
        maskb[b * 16384 + P] = (unsigned char)m;
    }
    __syncthreads();

    // ---- phase 1: masked channel sums (2 rows per sub) ----
    const int row0 = rowb + sub * 2;
    const float* fb = feats + (((long long)(b * 128 + c)) * 128 + row0) * 128 + colb;
    const unsigned int* mu32 = (const unsigned int*)msk;

    float s0 = 0.f, s1 = 0.f, s2 = 0.f, s3 = 0.f, s4 = 0.f, s5 = 0.f, sall = 0.f;
    for (int r = 0; r < 2; ++r) {
        const float4* row = (const float4*)(fb + r * 128);
        const unsigned int* mr = mu32 + (sub * 2 + r) * 8;
        #pragma unroll
        for (int j = 0; j < 8; ++j) {
            float4 v = row[j];
            unsigned int u = mr[j];
            unsigned int b0 = u, b1 = u >> 8, b2 = u >> 16, b3 = u >> 24;
            s0 += ((b0 >> 0) & 1) ? v.x : 0.f;  s1 += ((b0 >> 1) & 1) ? v.x : 0.f;
            s2 += ((b0 >> 2) & 1) ? v.x : 0.f;  s3 += ((b0 >> 3) & 1) ? v.x : 0.f;
            s4 += ((b0 >> 4) & 1) ? v.x : 0.f;  s5 += ((b0 >> 5) & 1) ? v.x : 0.f;
            s0 += ((b1 >> 0) & 1) ? v.y : 0.f;  s1 += ((b1 >> 1) & 1) ? v.y : 0.f;
            s2 += ((b1 >> 2) & 1) ? v.y : 0.f;  s3 += ((b1 >> 3) & 1) ? v.y : 0.f;
            s4 += ((b1 >> 4) & 1) ? v.y : 0.f;  s5 += ((b1 >> 5) & 1) ? v.y : 0.f;
            s0 += ((b2 >> 0) & 1) ? v.z : 0.f;  s1 += ((b2 >> 1) & 1) ? v.z : 0.f;
            s2 += ((b2 >> 2) & 1) ? v.z : 0.f;  s3 += ((b2 >> 3) & 1) ? v.z : 0.f;
            s4 += ((b2 >> 4) & 1) ? v.z : 0.f;  s5 += ((b2 >> 5) & 1) ? v.z : 0.f;
            s0 += ((b3 >> 0) & 1) ? v.w : 0.f;  s1 += ((b3 >> 1) & 1) ? v.w : 0.f;
            s2 += ((b3 >> 2) & 1) ? v.w : 0.f;  s3 += ((b3 >> 3) & 1) ? v.w : 0.f;
            s4 += ((b3 >> 4) & 1) ? v.w : 0.f;  s5 += ((b3 >> 5) & 1) ? v.w : 0.f;
            sall += v.x + v.y + v.z + v.w;
        }
    }
    if (sub > 0) {
        float* a = &accs[sub - 1][0][0];
        a[0 * 128 + c] = s0; a[1 * 128 + c] = s1; a[2 * 128 + c] = s2;
        a[3 * 128 + c] = s3; a[4 * 128 + c] = s4; a[5 * 128 + c] = s5;
        a[6 * 128 + c] = sall;
    }
    __syncthreads();
    if (sub == 0) {
        float* po = part + pidx * 896;
        po[0 * 128 + c] = s0 + accs[0][0][c] + accs[1][0][c] + accs[2][0][c];
        po[1 * 128 + c] = s1 + accs[0][1][c] + accs[1][1][c] + accs[2][1][c];
        po[2 * 128 + c] = s2 + accs[0][2][c] + accs[1][2][c] + accs[2][2][c];
        po[3 * 128 + c] = s3 + accs[0][3][c] + accs[1][3][c] + accs[2][3][c];
        po[4 * 128 + c] = s4 + accs[0][4][c] + accs[1][4][c] + accs[2][4][c];
        po[5 * 128 + c] = s5 + accs[0][5][c] + accs[1][5][c] + accs[2][5][c];
        po[6 * 128 + c] = sall + accs[0][6][c] + accs[1][6][c] + accs[2][6][c];
    }
}

// ---------------------------------------------------------------------------
// kernA2: combine quarters -> ctx -> LN1 -> gelu -> centersT + fused argmin
// (nearest prototype, first-index ties). 128 blocks x 512 threads.
// centersT layout: [row][128] (coalesced stores here, coalesced reads in
// kernD).
// ---------------------------------------------------------------------------
__global__ __launch_bounds__(512) void kernA2(
    const float* __restrict__ part, const unsigned char* __restrict__ maskb,
    const float* __restrict__ proto,
    const float* __restrict__ g1, const float* __restrict__ b1,
    float* __restrict__ centersT, int* __restrict__ nearest)
{
    __shared__ float ct[6][128];
    __shared__ int cnt[6];
    __shared__ float pl[48 * 129];     // proto, stride 129 -> 2-way banks (free)

    const int tid = threadIdx.x;
    const int p = blockIdx.x;                  // 0..127
    const int b = p >> 4, pp = p & 15, ihh = pp >> 2, iww = pp & 3;

    if (tid < 6) cnt[tid] = 0;
    for (int i = tid; i < 6144; i += 512)
        pl[(i >> 7) * 129 + (i & 127)] = proto[i];
    __syncthreads();

    // ---- counts from mask bytes (256 threads x 4 bytes, wave-reduced) ----
    if (tid < 256) {
        const unsigned char* mb = maskb + b * 16384 + ihh * 32 * 128 + iww * 32;
        int r = tid >> 3, jw = tid & 7;
        unsigned int u = *(const unsigned int*)(mb + r * 128 + jw * 4);
        #pragma unroll
        for (int k = 0; k < 6; ++k) {
            int cc = ((u >> k) & 1) + ((u >> (8 + k)) & 1) +
                     ((u >> (16 + k)) & 1) + ((u >> (24 + k)) & 1);
            #pragma unroll
            for (int m = 1; m < 64; m <<= 1) cc += __shfl_xor(cc, m, 64);
            if ((tid & 63) == 0 && cc) atomicAdd(&cnt[k], cc);
        }
    }
    __syncthreads();

    // ---- ctx closed form (768 items on 512 threads: STRIDED) ----
    const float* pb = part + (p * 4) * 896;
    for (int i = tid; i < 768; i += 512) {
        const int c = i & 127, k = i >> 7;
        float Sall = pb[6 * 128 + c] + pb[896 + 6 * 128 + c] +
                     pb[2 * 896 + 6 * 128 + c] + pb[3 * 896 + 6 * 128 + c];
        float Sk = pb[k * 128 + c] + pb[896 + k * 128 + c] +
                   pb[2 * 896 + k * 128 + c] + pb[3 * 896 + k * 128 + c];
        float Z = fmaf((float)cnt[k], E_M1, 1024.f);
        ct[k][c] = (Sall + E_M1 * Sk) / Z;
    }
    __syncthreads();

    // ---- LN over C + gelu -> centersT; fused nearest-proto argmin ----
    const int wv = tid >> 6, lane = tid & 63;
    if (wv < 6) {
        float x0 = ct[wv][lane], x1 = ct[wv][lane + 64];
        float s = x0 + x1;
        #pragma unroll
        for (int m = 1; m < 64; m <<= 1) s += __shfl_xor(s, m, 64);
        float mu = s * (1.f / 128.f);
        float d0 = x0 - mu, d1 = x1 - mu;
        float ss = d0 * d0 + d1 * d1;
        #pragma unroll
        for (int m = 1; m < 64; m <<= 1) ss += __shfl_xor(ss, m, 64);
        float inv = 1.f / sqrtf(ss * (1.f / 128.f) + 1e-6f);
        float y0 = d0 * inv * g1[lane] + b1[lane];
        float y1 = d1 * inv * g1[lane + 64] + b1[lane + 64];
        float z0 = gelu_exact(y0);
        float z1 = gelu_exact(y1);
        const int row = (b * 16 + pp) * 6 + wv;
        centersT[row * 128 + lane] = z0;           // [row][128] coalesced
        centersT[row * 128 + lane + 64] = z1;

        // argmin over 48 protos (strict < : first index wins, matches jnp)
        float best = INFINITY; int bi = 0;
        for (int k = 0; k < 48; ++k) {
            float t0 = z0 - pl[k * 129 + lane];
            float t1 = z1 - pl[k * 129 + 64 + lane];
            float sd = fmaf(t0, t0, t1 * t1);
            #pragma unroll
            for (int m = 1; m < 64; m <<= 1) sd += __shfl_xor(sd, m, 64);
            if (sd < best) { best = sd; bi = k; }
        }
        if (lane == 0) nearest[row] = bi;
    }
}

// ---------------------------------------------------------------------------
// kernD: momentum scan (parallel over k, ordered predicated loop) + pn2.
// centersT is [row][128]: per i, the 128 lanes read one contiguous 512B
// line (coalesced); unroll 8 keeps 8 loads in flight.
// ---------------------------------------------------------------------------
__global__ __launch_bounds__(128) void kernD(
    const float* __restrict__ proto0, const int* __restrict__ nearest,
    const float* __restrict__ centersT,
    float* __restrict__ proto_new, float* __restrict__ pn2,
    float* __restrict__ out_expand, float* __restrict__ out_proto)
{
    __shared__ int nl[768];
    __shared__ float wred[2];
    const int k = blockIdx.x, c = threadIdx.x;
    for (int i = c; i < 768; i += 128) nl[i] = nearest[i];
    __syncthreads();
    float p = proto0[k * 128 + c];
    const float OM = (float)(1.0 - 0.999);
    #pragma unroll 8
    for (int i = 0; i < 768; ++i) {
        float v = centersT[i * 128 + c];
        if (nl[i] == k) p = 0.999f * p + OM * v;
    }
    proto_new[k * 128 + c] = p;
    out_proto[k * 128 + c] = p;
    #pragma unroll
    for (int b = 0; b < 8; ++b) out_expand[(b * 48 + k) * 128 + c] = p;
    float sq = p * p;
    #pragma unroll
    for (int m = 1; m < 64; m <<= 1) sq += __shfl_xor(sq, m, 64);
    if ((c & 63) == 0) wred[c >> 6] = sq;
    __syncthreads();
    if (c == 0) pn2[k] = wred[0] + wred[1];
}

// ---------------------------------------------------------------------------
// kernE v5.1 (R7/R11-measured, ~51 µs): DMA fT staging + prot in LDS.
// 512 threads, 8 waves = (nh 2) x (cw 4). Wave (nh,cw): 32 n x 48 k x 32 c.
// Lane = 8 ng x 8 kg -> 4n x 6k. Per cq: 4 fT + 6 prot b128 reads feed 48
// pk_fma. Cross-cw reduce via red[4][48][66] (aliases dead fT+prot).
// grid (256,8) x 512. LDS 64000 B -> 2 blocks/CU, 16 waves/CU.
// ---------------------------------------------------------------------------
__global__ __launch_bounds__(512) void kernE(
    const float* __restrict__ feats, const float* __restrict__ proto_new,
    const float* __restrict__ pn2g,
    const float* __restrict__ g2, const float* __restrict__ b2,
    float* __restrict__ out_sim, float* __restrict__ out_dist,
    float* __restrict__ pred_small)
{
    __shared__ float smem[16000];
    float* fT   = smem;            // [128][64]   (dead after main loop)
    float* prot = smem + 8192;     // [48][132]   (dead after main loop)
    float* p4   = smem + 14528;    // [8][64]  F2 partials (F2 phase only)
    float* red  = smem;            // [4][48][66] (after main loop)
    float* dst  = smem + 12672;    // [64][49]    (combine phase on)
    float* lnA  = smem;            // [4][64]  LN partials (red dead by then)
    float* lnB  = smem + 256;      // [4][64]
    float* F2   = smem + 15808;    // [64]
    float* muv  = smem + 15872;    // [64]
    float* invv = smem + 15936;    // [64]

    const int t = threadIdx.x;
    const int b = blockIdx.y;
    const int nbase = blockIdx.x * 64;

    // ---- stage fT via 16B DMA (LDS byte off = idx*16 -> linear in lane) ----
    #pragma unroll
    for (int it = 0; it < 4; ++it) {
        int idx = it * 512 + t;              // 0..2047
        int c = idx >> 4, qd = idx & 15;
        gload16(feats + (((long long)(b * 128 + c)) << 14) + nbase + qd * 4,
                &fT[idx * 4]);
    }
    // ---- stage prot (register path; stride-132 rows are non-linear) ----
    for (int i4 = t; i4 < 1536; i4 += 512) {
        float4 v = ((const float4*)proto_new)[i4];
        *(float4*)&prot[(i4 >> 5) * 132 + (i4 & 31) * 4] = v;
    }
    __syncthreads();

    {   // F2[n] = sum_c f^2 (8 partials x 16 channels)
        int n = t & 63, cg = t >> 6;
        float s = 0.f;
        for (int c = cg * 16; c < cg * 16 + 16; ++c) { float x = fT[c * 64 + n]; s = fmaf(x, x, s); }
        p4[cg * 64 + n] = s;
    }
    __syncthreads();
    if (t < 64) {
        float s = 0.f;
        #pragma unroll
        for (int g = 0; g < 8; ++g) s += p4[g * 64 + t];
        F2[t] = s;          // read only after post-main barriers
    }

    // ---- main loop: wave (nh, cw); lane = (ng, kg) ----
    const int w = t >> 6, l = t & 63;
    const int cw = w & 3, nh = w >> 2;
    const int n0 = nh * 32 + (l & 7) * 4;   // 4 n per lane
    const int k0 = (l >> 3) * 6;            // 6 k per lane
    const int cbase = cw * 32;

    v2f acc[6][2];
    #pragma unroll
    for (int j = 0; j < 6; ++j) { acc[j][0] = splat2(0.f); acc[j][1] = splat2(0.f); }

    #pragma unroll
    for (int cq = 0; cq < 8; ++cq) {
        const int cb = cbase + cq * 4;
        v2f f[4][2];
        #pragma unroll
        for (int ch = 0; ch < 4; ++ch) {
            float4 a0 = *(const float4*)&fT[(cb + ch) * 64 + n0];
            f[ch][0] = *(v2f*)&a0.x; f[ch][1] = *(v2f*)&a0.z;
        }
        #pragma unroll
        for (int j = 0; j < 6; ++j) {
            float4 pv = *(const float4*)&prot[(k0 + j) * 132 + cb];
            v2f px = splat2(pv.x), py = splat2(pv.y), pz = splat2(pv.z), pw = splat2(pv.w);
            #pragma unroll
            for (int h = 0; h < 2; ++h) {
                acc[j][h] = __builtin_elementwise_fma(f[0][h], px,
                            __builtin_elementwise_fma(f[1][h], py,
                            __builtin_elementwise_fma(f[2][h], pz,
                            __builtin_elementwise_fma(f[3][h], pw, acc[j][h]))));
            }
        }
    }
    __syncthreads();   // fT & prot dead from here; region becomes red

    // ---- spill partials: red[cw][k][66-stride n]; nh halves disjoint ----
    #pragma unroll
    for (int j = 0; j < 6; ++j) {
        *(v2f*)&red[cw * 3168 + (k0 + j) * 66 + n0]     = acc[j][0];
        *(v2f*)&red[cw * 3168 + (k0 + j) * 66 + n0 + 2] = acc[j][1];
    }
    __syncthreads();

    // ---- combine 4 c-partials; 768 = (k, n-quad) cells on 512 threads ----
    for (int cell = t; cell < 768; cell += 512) {
        const int k = cell >> 4, n4 = (cell & 15) * 4;
        v2f lo = splat2(0.f), hi = splat2(0.f);
        #pragma unroll
        for (int ww = 0; ww < 4; ++ww) {
            lo += *(const v2f*)&red[ww * 3168 + k * 66 + n4];
            hi += *(const v2f*)&red[ww * 3168 + k * 66 + n4 + 2];
        }
        float pk = pn2g[k];
        float d0 = sqrtf(fmaxf(F2[n4 + 0] + pk - 2.f * lo.x, 0.f));
        float d1 = sqrtf(fmaxf(F2[n4 + 1] + pk - 2.f * lo.y, 0.f));
        float d2 = sqrtf(fmaxf(F2[n4 + 2] + pk - 2.f * hi.x, 0.f));
        float d3 = sqrtf(fmaxf(F2[n4 + 3] + pk - 2.f * hi.y, 0.f));
        float4 dv; dv.x = d0; dv.y = d1; dv.z = d2; dv.w = d3;
        *(float4*)(out_dist + (((long long)(b * 48 + k)) << 14) + nbase + n4) = dv;
        dst[(n4 + 0) * 49 + k] = 1.f / (1.f + 2.f * d0);
        dst[(n4 + 1) * 49 + k] = 1.f / (1.f + 2.f * d1);
        dst[(n4 + 2) * 49 + k] = 1.f / (1.f + 2.f * d2);
        dst[(n4 + 3) * 49 + k] = 1.f / (1.f + 2.f * d3);
    }
    __syncthreads();   // red dead from here; region becomes lnA/lnB

    // ---- LN stats per n: 256-thread partials, then combine ----
    if (t < 256) {
        const int n = t & 63, q = t >> 6;
        float s1 = 0.f, s2 = 0.f;
        for (int k = q * 12; k < q * 12 + 12; ++k) {
            float x = dst[n * 49 + k];
            s1 += x; s2 = fmaf(x, x, s2);
        }
        lnA[q * 64 + n] = s1;
        lnB[q * 64 + n] = s2;
    }
    __syncthreads();
    if (t < 64) {
        float s1 = ((lnA[t] + lnA[64 + t]) + lnA[128 + t]) + lnA[192 + t];
        float s2 = ((lnB[t] + lnB[64 + t]) + lnB[128 + t]) + lnB[192 + t];
        float mu = s1 * (1.f / 48.f);
        float var = fmaxf(s2 * (1.f / 48.f) - mu * mu, 0.f);
        muv[t] = mu;
        invv[t] = 1.f / sqrtf(var + 1e-6f);
    }
    __syncthreads();

    // ---- epilogue: 384 = (c6, n) items on 512 threads ----
    if (t < 384) {
        const int c6 = t >> 6, n = t & 63, ng = nbase + n;
        float mu = muv[n], inv = invv[n];
        float pm = 0.f;
        #pragma unroll
        for (int kp = 0; kp < 8; ++kp) {
            int k = kp * 6 + c6;
            float y = (dst[n * 49 + k] - mu) * inv * g2[k] + b2[k];
            float z = gelu_exact(y);
            out_sim[(((long long)(b * 48 + k)) << 14) + ng] = z;
            pm = (kp == 0) ? z : fmaxf(pm, z);
        }
        pred_small[((b * 6 + c6) << 14) + ng] = pm;
    }
}

// ---------------------------------------------------------------------------
// kernF: half-pixel bilinear x4 upsample (8,6,128,128)->(8,6,512,512)
// ---------------------------------------------------------------------------
__global__ __launch_bounds__(256) void kernF(
    const float* __restrict__ ps, float* __restrict__ pred)
{
    int idx = blockIdx.x * 256 + threadIdx.x;    // 3,145,728
    int xq = idx & 127;
    int oy = (idx >> 7) & 511;
    int bc = idx >> 16;
    int qy = oy >> 2, ry = oy & 3;
    int y0 = qy + ((ry < 2) ? -1 : 0);
    float fy = (ry == 0) ? 0.625f : (ry == 1) ? 0.875f : (ry == 2) ? 0.125f : 0.375f;
    int y0c = max(y0, 0), y1c = min(y0 + 1, 127);
    const float* base = ps + bc * 16384;
    const float* rA = base + y0c * 128;
    const float* rB = base + y1c * 128;
    int xm = max(xq - 1, 0), xp = min(xq + 1, 127);
    float a0 = rA[xm], a1 = rA[xq], a2 = rA[xp];
    float c0 = rB[xm], c1 = rB[xq], c2 = rB[xp];
    float w0 = 1.f - fy;
    float gm = w0 * a0 + fy * c0;
    float gc = w0 * a1 + fy * c1;
    float gp = w0 * a2 + fy * c2;
    float4 o;
    o.x = 0.375f * gm + 0.625f * gc;
    o.y = 0.125f * gm + 0.875f * gc;
    o.z = 0.875f * gc + 0.125f * gp;
    o.w = 0.625f * gc + 0.375f * gp;
    *(float4*)(pred + ((long long)idx << 2)) = o;
}

// ---------------------------------------------------------------------------
extern "C" void kernel_launch(void* const* d_in, const int* in_sizes, int n_in,
                              void* d_out, int out_size, void* d_ws, size_t ws_size,
                              hipStream_t stream)
{
    const float* feats = (const float*)d_in[0];
    const int* gt = (const int*)d_in[1];
    const float* proto = (const float*)d_in[2];
    const float* g1 = (const float*)d_in[3];
    const float* b1 = (const float*)d_in[4];
    const float* g2 = (const float*)d_in[5];
    const float* b2 = (const float*)d_in[6];

    float* out = (float*)d_out;
    float* pred       = out;
    float* out_expand = out + 12582912;
    float* out_sim    = out + 12632064;
    float* out_dist   = out + 18923520;
    float* out_proto  = out + 25214976;

    float* ws = (float*)d_ws;
    float* centersT   = ws + 98304;             // 98,304 (slot 0 unused)
    float* proto_new  = ws + 196608;            // 6,144
    float* pn2        = ws + 202752;            // 64
    int*   nearest    = (int*)(ws + 202816);    // 768
    float* part       = ws + 203584;            // 512*896 = 458,752
    float* pred_small = ws + 203584;            // ALIASED: kernE writes after
                                                // kernA2's last read of part
    unsigned char* maskb = (unsigned char*)(ws + 990016); // 131,072 B

    kernA1<<<512, 512, 0, stream>>>(feats, gt, maskb, part);
    kernA2<<<128, 512, 0, stream>>>(part, maskb, proto, g1, b1, centersT, nearest);
    kernD <<<48, 128, 0, stream>>>(proto, nearest, centersT, proto_new, pn2,
                                   out_expand, out_proto);
    kernE <<<dim3(256, 8), 512, 0, stream>>>(feats, proto_new, pn2, g2, b2,
                                             out_sim, out_dist, pred_small);
    kernF<<<12288, 256, 0, stream>>>(pred_small, pred);
}

// Round 14
// 281.497 us; speedup vs baseline: 1.1481x; 1.1481x over previous
//
#include <hip/hip_runtime.h>
#include <hip/hip_bf16.h>
#include <math.h>

// ---------------------------------------------------------------------------
// CLSNet forward. B=8, C=128, H=W=128, Horg=Worg=512, NC=6, KP=8, NPROTO=48,
// PH=PW=4 (patches 32x32), 128 patches, 768 center rows.
// Outputs: pred[8,6,512,512] | proto_expand[8,48,128] | p2c[8,48,128,128] |
// distance_l2[8,48,16384] | proto_new[48,128]
// gt arrives as int32.
// R13 post-mortem: layout flip [row][128] made kernD 94.7 µs — VGPR=8 shows
// the compiler serialized 768 scalar loads (no ILP, no TLP at 48 blocks).
// R14 fix: kernD v3 decouples loads from the serial momentum chain via LDS
// chunking — per 64-row chunk, 128 threads cooperatively load 32 KB (16
// independent float4 each, coalesced, in flight), then the ordered scan
// reads LDS. Same arithmetic, same order. kernA2's coalesced [row][128]
// stores kept. kernE v5.1 / kernA1 v4 unchanged (R11-measured).
// ---------------------------------------------------------------------------

#define E_M1 1.71828182845904523536f   // e - 1
#define INV_SQRT2 0.70710678118654752440f

typedef float v2f __attribute__((ext_vector_type(2)));

__device__ __forceinline__ float gelu_exact(float x) {
    return 0.5f * x * (1.f + erff(x * INV_SQRT2));
}
__device__ __forceinline__ v2f splat2(float x) { v2f r; r.x = x; r.y = x; return r; }

// async 16-B global -> LDS DMA (gfx950). LDS dest must be wave-uniform
// base + lane*16 at the issuing instruction — caller guarantees linearity.
__device__ __forceinline__ void gload16(const float* g, float* l) {
    __builtin_amdgcn_global_load_lds(
        (const __attribute__((address_space(1))) void*)g,
        (__attribute__((address_space(3))) void*)l, 16, 0, 0);
}

// ---------------------------------------------------------------------------
// kernA1 v4: fused mask-gen + per-(patch,quarter) segmented channel sums.
// 512 blocks x 512 threads. Phase 0 (t<256): scrambled one-hot 6-bit mask
// for the block's 8x32 pixel region (verbatim kern0b formula) -> LDS msk +
// global maskb (consumed by kernA2). Phase 1: gather, sub = t>>7 handles
// 2 of the 8 rows; LDS combine. part layout: part[pidx][7][128].
// ---------------------------------------------------------------------------
__global__ __launch_bounds__(512) void kernA1(
    const float* __restrict__ feats, const int* __restrict__ gt,
    unsigned char* __restrict__ maskb, float* __restrict__ part)
{
    __shared__ float accs[3][7][128];
    __shared__ unsigned char msk[256];          // [8 rows][32 cols]
    const int pidx = blockIdx.x;
    const int patch = pidx >> 2, q = pidx & 3;
    const int b = patch >> 4, pp = patch & 15, ihh = pp >> 2, iww = pp & 3;
    const int c = threadIdx.x & 127, sub = threadIdx.x >> 7;
    const int rowb = ihh * 32 + q * 8, colb = iww * 32;

    // ---- phase 0: mask bytes for this block's 256 pixels ----
    if (threadIdx.x < 256) {
        const int prow = threadIdx.x >> 5, pcol = threadIdx.x & 31;
        const int P = (rowb + prow) * 128 + colb + pcol;
        const int* gb = gt + b * 262144;
        unsigned int m = 0;
        #pragma unroll
        for (int cc = 0; cc < 6; ++cc) {
            int pos = cc * 16384 + P;
            int hp = pos / 768;
            int rem = pos - hp * 768;
            int wp = rem / 6;
            int kp = rem - wp * 6;
            int g = gb[(4 * hp) * 512 + 4 * wp];
            int lab = (g == 6) ? 0 : g;
            if (lab == kp) m |= (1u << cc);
        }
        msk[threadIdx.x] = (unsigned char)m;
        maskb[b * 16384 + P] = (unsigned char)m;
    }
    __syncthreads();

    // ---- phase 1: masked channel sums (2 rows per sub) ----
    const int row0 = rowb + sub * 2;
    const float* fb = feats + (((long long)(b * 128 + c)) * 128 + row0) * 128 + colb;
    const unsigned int* mu32 = (const unsigned int*)msk;

    float s0 = 0.f, s1 = 0.f, s2 = 0.f, s3 = 0.f, s4 = 0.f, s5 = 0.f, sall = 0.f;
    for (int r = 0; r < 2; ++r) {
        const float4* row = (const float4*)(fb + r * 128);
        const unsigned int* mr = mu32 + (sub * 2 + r) * 8;
        #pragma unroll
        for (int j = 0; j < 8; ++j) {
            float4 v = row[j];
            unsigned int u = mr[j];
            unsigned int b0 = u, b1 = u >> 8, b2 = u >> 16, b3 = u >> 24;
            s0 += ((b0 >> 0) & 1) ? v.x : 0.f;  s1 += ((b0 >> 1) & 1) ? v.x : 0.f;
            s2 += ((b0 >> 2) & 1) ? v.x : 0.f;  s3 += ((b0 >> 3) & 1) ? v.x : 0.f;
            s4 += ((b0 >> 4) & 1) ? v.x : 0.f;  s5 += ((b0 >> 5) & 1) ? v.x : 0.f;
            s0 += ((b1 >> 0) & 1) ? v.y : 0.f;  s1 += ((b1 >> 1) & 1) ? v.y : 0.f;
            s2 += ((b1 >> 2) & 1) ? v.y : 0.f;  s3 += ((b1 >> 3) & 1) ? v.y : 0.f;
            s4 += ((b1 >> 4) & 1) ? v.y : 0.f;  s5 += ((b1 >> 5) & 1) ? v.y : 0.f;
            s0 += ((b2 >> 0) & 1) ? v.z : 0.f;  s1 += ((b2 >> 1) & 1) ? v.z : 0.f;
            s2 += ((b2 >> 2) & 1) ? v.z : 0.f;  s3 += ((b2 >> 3) & 1) ? v.z : 0.f;
            s4 += ((b2 >> 4) & 1) ? v.z : 0.f;  s5 += ((b2 >> 5) & 1) ? v.z : 0.f;
            s0 += ((b3 >> 0) & 1) ? v.w : 0.f;  s1 += ((b3 >> 1) & 1) ? v.w : 0.f;
            s2 += ((b3 >> 2) & 1) ? v.w : 0.f;  s3 += ((b3 >> 3) & 1) ? v.w : 0.f;
            s4 += ((b3 >> 4) & 1) ? v.w : 0.f;  s5 += ((b3 >> 5) & 1) ? v.w : 0.f;
            sall += v.x + v.y + v.z + v.w;
        }
    }
    if (sub > 0) {
        float* a = &accs[sub - 1][0][0];
        a[0 * 128 + c] = s0; a[1 * 128 + c] = s1; a[2 * 128 + c] = s2;
        a[3 * 128 + c] = s3; a[4 * 128 + c] = s4; a[5 * 128 + c] = s5;
        a[6 * 128 + c] = sall;
    }
    __syncthreads();
    if (sub == 0) {
        float* po = part + pidx * 896;
        po[0 * 128 + c] = s0 + accs[0][0][c] + accs[1][0][c] + accs[2][0][c];
        po[1 * 128 + c] = s1 + accs[0][1][c] + accs[1][1][c] + accs[2][1][c];
        po[2 * 128 + c] = s2 + accs[0][2][c] + accs[1][2][c] + accs[2][2][c];
        po[3 * 128 + c] = s3 + accs[0][3][c] + accs[1][3][c] + accs[2][3][c];
        po[4 * 128 + c] = s4 + accs[0][4][c] + accs[1][4][c] + accs[2][4][c];
        po[5 * 128 + c] = s5 + accs[0][5][c] + accs[1][5][c] + accs[2][5][c];
        po[6 * 128 + c] = sall + accs[0][6][c] + accs[1][6][c] + accs[2][6][c];
    }
}

// ---------------------------------------------------------------------------
// kernA2: combine quarters -> ctx -> LN1 -> gelu -> centersT + fused argmin
// (nearest prototype, first-index ties). 128 blocks x 512 threads.
// centersT layout: [row][128] (coalesced stores here, coalesced wave-level
// reads in kernD).
// ---------------------------------------------------------------------------
__global__ __launch_bounds__(512) void kernA2(
    const float* __restrict__ part, const unsigned char* __restrict__ maskb,
    const float* __restrict__ proto,
    const float* __restrict__ g1, const float* __restrict__ b1,
    float* __restrict__ centersT, int* __restrict__ nearest)
{
    __shared__ float ct[6][128];
    __shared__ int cnt[6];
    __shared__ float pl[48 * 129];     // proto, stride 129 -> 2-way banks (free)

    const int tid = threadIdx.x;
    const int p = blockIdx.x;                  // 0..127
    const int b = p >> 4, pp = p & 15, ihh = pp >> 2, iww = pp & 3;

    if (tid < 6) cnt[tid] = 0;
    for (int i = tid; i < 6144; i += 512)
        pl[(i >> 7) * 129 + (i & 127)] = proto[i];
    __syncthreads();

    // ---- counts from mask bytes (256 threads x 4 bytes, wave-reduced) ----
    if (tid < 256) {
        const unsigned char* mb = maskb + b * 16384 + ihh * 32 * 128 + iww * 32;
        int r = tid >> 3, jw = tid & 7;
        unsigned int u = *(const unsigned int*)(mb + r * 128 + jw * 4);
        #pragma unroll
        for (int k = 0; k < 6; ++k) {
            int cc = ((u >> k) & 1) + ((u >> (8 + k)) & 1) +
                     ((u >> (16 + k)) & 1) + ((u >> (24 + k)) & 1);
            #pragma unroll
            for (int m = 1; m < 64; m <<= 1) cc += __shfl_xor(cc, m, 64);
            if ((tid & 63) == 0 && cc) atomicAdd(&cnt[k], cc);
        }
    }
    __syncthreads();

    // ---- ctx closed form (768 items on 512 threads: STRIDED) ----
    const float* pb = part + (p * 4) * 896;
    for (int i = tid; i < 768; i += 512) {
        const int c = i & 127, k = i >> 7;
        float Sall = pb[6 * 128 + c] + pb[896 + 6 * 128 + c] +
                     pb[2 * 896 + 6 * 128 + c] + pb[3 * 896 + 6 * 128 + c];
        float Sk = pb[k * 128 + c] + pb[896 + k * 128 + c] +
                   pb[2 * 896 + k * 128 + c] + pb[3 * 896 + k * 128 + c];
        float Z = fmaf((float)cnt[k], E_M1, 1024.f);
        ct[k][c] = (Sall + E_M1 * Sk) / Z;
    }
    __syncthreads();

    // ---- LN over C + gelu -> centersT; fused nearest-proto argmin ----
    const int wv = tid >> 6, lane = tid & 63;
    if (wv < 6) {
        float x0 = ct[wv][lane], x1 = ct[wv][lane + 64];
        float s = x0 + x1;
        #pragma unroll
        for (int m = 1; m < 64; m <<= 1) s += __shfl_xor(s, m, 64);
        float mu = s * (1.f / 128.f);
        float d0 = x0 - mu, d1 = x1 - mu;
        float ss = d0 * d0 + d1 * d1;
        #pragma unroll
        for (int m = 1; m < 64; m <<= 1) ss += __shfl_xor(ss, m, 64);
        float inv = 1.f / sqrtf(ss * (1.f / 128.f) + 1e-6f);
        float y0 = d0 * inv * g1[lane] + b1[lane];
        float y1 = d1 * inv * g1[lane + 64] + b1[lane + 64];
        float z0 = gelu_exact(y0);
        float z1 = gelu_exact(y1);
        const int row = (b * 16 + pp) * 6 + wv;
        centersT[row * 128 + lane] = z0;           // [row][128] coalesced
        centersT[row * 128 + lane + 64] = z1;

        // argmin over 48 protos (strict < : first index wins, matches jnp)
        float best = INFINITY; int bi = 0;
        for (int k = 0; k < 48; ++k) {
            float t0 = z0 - pl[k * 129 + lane];
            float t1 = z1 - pl[k * 129 + 64 + lane];
            float sd = fmaf(t0, t0, t1 * t1);
            #pragma unroll
            for (int m = 1; m < 64; m <<= 1) sd += __shfl_xor(sd, m, 64);
            if (sd < best) { best = sd; bi = k; }
        }
        if (lane == 0) nearest[row] = bi;
    }
}

// ---------------------------------------------------------------------------
// kernD v3: momentum scan with LDS-chunked loads. Per 64-row chunk, the 128
// threads cooperatively load 32 KB of centersT [row][128] (16 independent
// float4 each, coalesced, all in flight), then the ORDERED scan reads LDS
// (wait-free). Same arithmetic & order as the serial form. 48 blocks x 128.
// ---------------------------------------------------------------------------
__global__ __launch_bounds__(128) void kernD(
    const float* __restrict__ proto0, const int* __restrict__ nearest,
    const float* __restrict__ centersT,
    float* __restrict__ proto_new, float* __restrict__ pn2,
    float* __restrict__ out_expand, float* __restrict__ out_proto)
{
    __shared__ int nl[768];
    __shared__ float4 tile4[2048];     // [64 rows][128 c] = 32 KB
    __shared__ float wred[2];
    const int k = blockIdx.x, c = threadIdx.x;
    for (int i = c; i < 768; i += 128) nl[i] = nearest[i];
    __syncthreads();
    float p = proto0[k * 128 + c];
    const float OM = (float)(1.0 - 0.999);
    const float* tile = (const float*)tile4;

    for (int chunk = 0; chunk < 12; ++chunk) {
        const float4* src = (const float4*)(centersT + chunk * 8192);
        #pragma unroll
        for (int j = 0; j < 16; ++j)
            tile4[j * 128 + c] = src[j * 128 + c];   // 16 independent loads
        __syncthreads();
        const int ib = chunk * 64;
        #pragma unroll 8
        for (int r = 0; r < 64; ++r) {
            float v = tile[r * 128 + c];
            if (nl[ib + r] == k) p = 0.999f * p + OM * v;
        }
        __syncthreads();
    }

    proto_new[k * 128 + c] = p;
    out_proto[k * 128 + c] = p;
    #pragma unroll
    for (int b = 0; b < 8; ++b) out_expand[(b * 48 + k) * 128 + c] = p;
    float sq = p * p;
    #pragma unroll
    for (int m = 1; m < 64; m <<= 1) sq += __shfl_xor(sq, m, 64);
    if ((c & 63) == 0) wred[c >> 6] = sq;
    __syncthreads();
    if (c == 0) pn2[k] = wred[0] + wred[1];
}

// ---------------------------------------------------------------------------
// kernE v5.1 (R7/R11-measured, ~51 µs): DMA fT staging + prot in LDS.
// 512 threads, 8 waves = (nh 2) x (cw 4). Wave (nh,cw): 32 n x 48 k x 32 c.
// Lane = 8 ng x 8 kg -> 4n x 6k. Per cq: 4 fT + 6 prot b128 reads feed 48
// pk_fma. Cross-cw reduce via red[4][48][66] (aliases dead fT+prot).
// grid (256,8) x 512. LDS 64000 B -> 2 blocks/CU, 16 waves/CU.
// ---------------------------------------------------------------------------
__global__ __launch_bounds__(512) void kernE(
    const float* __restrict__ feats, const float* __restrict__ proto_new,
    const float* __restrict__ pn2g,
    const float* __restrict__ g2, const float* __restrict__ b2,
    float* __restrict__ out_sim, float* __restrict__ out_dist,
    float* __restrict__ pred_small)
{
    __shared__ float smem[16000];
    float* fT   = smem;            // [128][64]   (dead after main loop)
    float* prot = smem + 8192;     // [48][132]   (dead after main loop)
    float* p4   = smem + 14528;    // [8][64]  F2 partials (F2 phase only)
    float* red  = smem;            // [4][48][66] (after main loop)
    float* dst  = smem + 12672;    // [64][49]    (combine phase on)
    float* lnA  = smem;            // [4][64]  LN partials (red dead by then)
    float* lnB  = smem + 256;      // [4][64]
    float* F2   = smem + 15808;    // [64]
    float* muv  = smem + 15872;    // [64]
    float* invv = smem + 15936;    // [64]

    const int t = threadIdx.x;
    const int b = blockIdx.y;
    const int nbase = blockIdx.x * 64;

    // ---- stage fT via 16B DMA (LDS byte off = idx*16 -> linear in lane) ----
    #pragma unroll
    for (int it = 0; it < 4; ++it) {
        int idx = it * 512 + t;              // 0..2047
        int c = idx >> 4, qd = idx & 15;
        gload16(feats + (((long long)(b * 128 + c)) << 14) + nbase + qd * 4,
                &fT[idx * 4]);
    }
    // ---- stage prot (register path; stride-132 rows are non-linear) ----
    for (int i4 = t; i4 < 1536; i4 += 512) {
        float4 v = ((const float4*)proto_new)[i4];
        *(float4*)&prot[(i4 >> 5) * 132 + (i4 & 31) * 4] = v;
    }
    __syncthreads();

    {   // F2[n] = sum_c f^2 (8 partials x 16 channels)
        int n = t & 63, cg = t >> 6;
        float s = 0.f;
        for (int c = cg * 16; c < cg * 16 + 16; ++c) { float x = fT[c * 64 + n]; s = fmaf(x, x, s); }
        p4[cg * 64 + n] = s;
    }
    __syncthreads();
    if (t < 64) {
        float s = 0.f;
        #pragma unroll
        for (int g = 0; g < 8; ++g) s += p4[g * 64 + t];
        F2[t] = s;          // read only after post-main barriers
    }

    // ---- main loop: wave (nh, cw); lane = (ng, kg) ----
    const int w = t >> 6, l = t & 63;
    const int cw = w & 3, nh = w >> 2;
    const int n0 = nh * 32 + (l & 7) * 4;   // 4 n per lane
    const int k0 = (l >> 3) * 6;            // 6 k per lane
    const int cbase = cw * 32;

    v2f acc[6][2];
    #pragma unroll
    for (int j = 0; j < 6; ++j) { acc[j][0] = splat2(0.f); acc[j][1] = splat2(0.f); }

    #pragma unroll
    for (int cq = 0; cq < 8; ++cq) {
        const int cb = cbase + cq * 4;
        v2f f[4][2];
        #pragma unroll
        for (int ch = 0; ch < 4; ++ch) {
            float4 a0 = *(const float4*)&fT[(cb + ch) * 64 + n0];
            f[ch][0] = *(v2f*)&a0.x; f[ch][1] = *(v2f*)&a0.z;
        }
        #pragma unroll
        for (int j = 0; j < 6; ++j) {
            float4 pv = *(const float4*)&prot[(k0 + j) * 132 + cb];
            v2f px = splat2(pv.x), py = splat2(pv.y), pz = splat2(pv.z), pw = splat2(pv.w);
            #pragma unroll
            for (int h = 0; h < 2; ++h) {
                acc[j][h] = __builtin_elementwise_fma(f[0][h], px,
                            __builtin_elementwise_fma(f[1][h], py,
                            __builtin_elementwise_fma(f[2][h], pz,
                            __builtin_elementwise_fma(f[3][h], pw, acc[j][h]))));
            }
        }
    }
    __syncthreads();   // fT & prot dead from here; region becomes red

    // ---- spill partials: red[cw][k][66-stride n]; nh halves disjoint ----
    #pragma unroll
    for (int j = 0; j < 6; ++j) {
        *(v2f*)&red[cw * 3168 + (k0 + j) * 66 + n0]     = acc[j][0];
        *(v2f*)&red[cw * 3168 + (k0 + j) * 66 + n0 + 2] = acc[j][1];
    }
    __syncthreads();

    // ---- combine 4 c-partials; 768 = (k, n-quad) cells on 512 threads ----
    for (int cell = t; cell < 768; cell += 512) {
        const int k = cell >> 4, n4 = (cell & 15) * 4;
        v2f lo = splat2(0.f), hi = splat2(0.f);
        #pragma unroll
        for (int ww = 0; ww < 4; ++ww) {
            lo += *(const v2f*)&red[ww * 3168 + k * 66 + n4];
            hi += *(const v2f*)&red[ww * 3168 + k * 66 + n4 + 2];
        }
        float pk = pn2g[k];
        float d0 = sqrtf(fmaxf(F2[n4 + 0] + pk - 2.f * lo.x, 0.f));
        float d1 = sqrtf(fmaxf(F2[n4 + 1] + pk - 2.f * lo.y, 0.f));
        float d2 = sqrtf(fmaxf(F2[n4 + 2] + pk - 2.f * hi.x, 0.f));
        float d3 = sqrtf(fmaxf(F2[n4 + 3] + pk - 2.f * hi.y, 0.f));
        float4 dv; dv.x = d0; dv.y = d1; dv.z = d2; dv.w = d3;
        *(float4*)(out_dist + (((long long)(b * 48 + k)) << 14) + nbase + n4) = dv;
        dst[(n4 + 0) * 49 + k] = 1.f / (1.f + 2.f * d0);
        dst[(n4 + 1) * 49 + k] = 1.f / (1.f + 2.f * d1);
        dst[(n4 + 2) * 49 + k] = 1.f / (1.f + 2.f * d2);
        dst[(n4 + 3) * 49 + k] = 1.f / (1.f + 2.f * d3);
    }
    __syncthreads();   // red dead from here; region becomes lnA/lnB

    // ---- LN stats per n: 256-thread partials, then combine ----
    if (t < 256) {
        const int n = t & 63, q = t >> 6;
        float s1 = 0.f, s2 = 0.f;
        for (int k = q * 12; k < q * 12 + 12; ++k) {
            float x = dst[n * 49 + k];
            s1 += x; s2 = fmaf(x, x, s2);
        }
        lnA[q * 64 + n] = s1;
        lnB[q * 64 + n] = s2;
    }
    __syncthreads();
    if (t < 64) {
        float s1 = ((lnA[t] + lnA[64 + t]) + lnA[128 + t]) + lnA[192 + t];
        float s2 = ((lnB[t] + lnB[64 + t]) + lnB[128 + t]) + lnB[192 + t];
        float mu = s1 * (1.f / 48.f);
        float var = fmaxf(s2 * (1.f / 48.f) - mu * mu, 0.f);
        muv[t] = mu;
        invv[t] = 1.f / sqrtf(var + 1e-6f);
    }
    __syncthreads();

    // ---- epilogue: 384 = (c6, n) items on 512 threads ----
    if (t < 384) {
        const int c6 = t >> 6, n = t & 63, ng = nbase + n;
        float mu = muv[n], inv = invv[n];
        float pm = 0.f;
        #pragma unroll
        for (int kp = 0; kp < 8; ++kp) {
            int k = kp * 6 + c6;
            float y = (dst[n * 49 + k] - mu) * inv * g2[k] + b2[k];
            float z = gelu_exact(y);
            out_sim[(((long long)(b * 48 + k)) << 14) + ng] = z;
            pm = (kp == 0) ? z : fmaxf(pm, z);
        }
        pred_small[((b * 6 + c6) << 14) + ng] = pm;
    }
}

// ---------------------------------------------------------------------------
// kernF: half-pixel bilinear x4 upsample (8,6,128,128)->(8,6,512,512)
// ---------------------------------------------------------------------------
__global__ __launch_bounds__(256) void kernF(
    const float* __restrict__ ps, float* __restrict__ pred)
{
    int idx = blockIdx.x * 256 + threadIdx.x;    // 3,145,728
    int xq = idx & 127;
    int oy = (idx >> 7) & 511;
    int bc = idx >> 16;
    int qy = oy >> 2, ry = oy & 3;
    int y0 = qy + ((ry < 2) ? -1 : 0);
    float fy = (ry == 0) ? 0.625f : (ry == 1) ? 0.875f : (ry == 2) ? 0.125f : 0.375f;
    int y0c = max(y0, 0), y1c = min(y0 + 1, 127);
    const float* base = ps + bc * 16384;
    const float* rA = base + y0c * 128;
    const float* rB = base + y1c * 128;
    int xm = max(xq - 1, 0), xp = min(xq + 1, 127);
    float a0 = rA[xm], a1 = rA[xq], a2 = rA[xp];
    float c0 = rB[xm], c1 = rB[xq], c2 = rB[xp];
    float w0 = 1.f - fy;
    float gm = w0 * a0 + fy * c0;
    float gc = w0 * a1 + fy * c1;
    float gp = w0 * a2 + fy * c2;
    float4 o;
    o.x = 0.375f * gm + 0.625f * gc;
    o.y = 0.125f * gm + 0.875f * gc;
    o.z = 0.875f * gc + 0.125f * gp;
    o.w = 0.625f * gc + 0.375f * gp;
    *(float4*)(pred + ((long long)idx << 2)) = o;
}

// ---------------------------------------------------------------------------
extern "C" void kernel_launch(void* const* d_in, const int* in_sizes, int n_in,
                              void* d_out, int out_size, void* d_ws, size_t ws_size,
                              hipStream_t stream)
{
    const float* feats = (const float*)d_in[0];
    const int* gt = (const int*)d_in[1];
    const float* proto = (const float*)d_in[2];
    const float* g1 = (const float*)d_in[3];
    const float* b1 = (const float*)d_in[4];
    const float* g2 = (const float*)d_in[5];
    const float* b2 = (const float*)d_in[6];

    float* out = (float*)d_out;
    float* pred       = out;
    float* out_expand = out + 12582912;
    float* out_sim    = out + 12632064;
    float* out_dist   = out + 18923520;
    float* out_proto  = out + 25214976;

    float* ws = (float*)d_ws;
    float* centersT   = ws + 98304;             // 98,304 (slot 0 unused)
    float* proto_new  = ws + 196608;            // 6,144
    float* pn2        = ws + 202752;            // 64
    int*   nearest    = (int*)(ws + 202816);    // 768
    float* part       = ws + 203584;            // 512*896 = 458,752
    float* pred_small = ws + 203584;            // ALIASED: kernE writes after
                                                // kernA2's last read of part
    unsigned char* maskb = (unsigned char*)(ws + 990016); // 131,072 B

    kernA1<<<512, 512, 0, stream>>>(feats, gt, maskb, part);
    kernA2<<<128, 512, 0, stream>>>(part, maskb, proto, g1, b1, centersT, nearest);
    kernD <<<48, 128, 0, stream>>>(proto, nearest, centersT, proto_new, pn2,
                                   out_expand, out_proto);
    kernE <<<dim3(256, 8), 512, 0, stream>>>(feats, proto_new, pn2, g2, b2,
                                             out_sim, out_dist, pred_small);
    kernF<<<12288, 256, 0, stream>>>(pred_small, pred);
}

// Round 15
// 246.553 us; speedup vs baseline: 1.3108x; 1.1417x over previous
//
#include <hip/hip_runtime.h>
#include <hip/hip_bf16.h>
#include <math.h>

// ---------------------------------------------------------------------------
// CLSNet forward. B=8, C=128, H=W=128, Horg=Worg=512, NC=6, KP=8, NPROTO=48,
// PH=PW=4 (patches 32x32), 128 patches, 768 center rows.
// Outputs: pred[8,6,512,512] | proto_expand[8,48,128] | p2c[8,48,128,128] |
// distance_l2[8,48,16384] | proto_new[48,128]
// gt arrives as int32.
// R14 post-mortem: kernD attribution across R11/R13/R14: old scatter ~31.6,
// serial [row][128] 94.7, LDS-chunked 53 — "read all 768 rows" is the flaw.
// R15: kernD v4 uses the closed form of the momentum recurrence:
// p = 0.999^m p0 + sum_j 0.001*0.999^(m-1-j) v_ij. Ballot-compacted ordered
// match list (~16 rows/k avg), weighted gather of ONLY matching rows
// (contiguous 512B in [row][128]), weights as iterated products (w*=0.999).
// kernE v5.1 / kernA1 v4 / kernA2 [row][128] unchanged (measured).
// ---------------------------------------------------------------------------

#define E_M1 1.71828182845904523536f   // e - 1
#define INV_SQRT2 0.70710678118654752440f

typedef float v2f __attribute__((ext_vector_type(2)));

__device__ __forceinline__ float gelu_exact(float x) {
    return 0.5f * x * (1.f + erff(x * INV_SQRT2));
}
__device__ __forceinline__ v2f splat2(float x) { v2f r; r.x = x; r.y = x; return r; }

// async 16-B global -> LDS DMA (gfx950). LDS dest must be wave-uniform
// base + lane*16 at the issuing instruction — caller guarantees linearity.
__device__ __forceinline__ void gload16(const float* g, float* l) {
    __builtin_amdgcn_global_load_lds(
        (const __attribute__((address_space(1))) void*)g,
        (__attribute__((address_space(3))) void*)l, 16, 0, 0);
}

// ---------------------------------------------------------------------------
// kernA1 v4: fused mask-gen + per-(patch,quarter) segmented channel sums.
// 512 blocks x 512 threads. Phase 0 (t<256): scrambled one-hot 6-bit mask
// for the block's 8x32 pixel region (verbatim kern0b formula) -> LDS msk +
// global maskb (consumed by kernA2). Phase 1: gather, sub = t>>7 handles
// 2 of the 8 rows; LDS combine. part layout: part[pidx][7][128].
// ---------------------------------------------------------------------------
__global__ __launch_bounds__(512) void kernA1(
    const float* __restrict__ feats, const int* __restrict__ gt,
    unsigned char* __restrict__ maskb, float* __restrict__ part)
{
    __shared__ float accs[3][7][128];
    __shared__ unsigned char msk[256];          // [8 rows][32 cols]
    const int pidx = blockIdx.x;
    const int patch = pidx >> 2, q = pidx & 3;
    const int b = patch >> 4, pp = patch & 15, ihh = pp >> 2, iww = pp & 3;
    const int c = threadIdx.x & 127, sub = threadIdx.x >> 7;
    const int rowb = ihh * 32 + q * 8, colb = iww * 32;

    // ---- phase 0: mask bytes for this block's 256 pixels ----
    if (threadIdx.x < 256) {
        const int prow = threadIdx.x >> 5, pcol = threadIdx.x & 31;
        const int P = (rowb + prow) * 128 + colb + pcol;
        const int* gb = gt + b * 262144;
        unsigned int m = 0;
        #pragma unroll
        for (int cc = 0; cc < 6; ++cc) {
            int pos = cc * 16384 + P;
            int hp = pos / 768;
            int rem = pos - hp * 768;
            int wp = rem / 6;
            int kp = rem - wp * 6;
            int g = gb[(4 * hp) * 512 + 4 * wp];
            int lab = (g == 6) ? 0 : g;
            if (lab == kp) m |= (1u << cc);
        }
        msk[threadIdx.x] = (unsigned char)m;
        maskb[b * 16384 + P] = (unsigned char)m;
    }
    __syncthreads();

    // ---- phase 1: masked channel sums (2 rows per sub) ----
    const int row0 = rowb + sub * 2;
    const float* fb = feats + (((long long)(b * 128 + c)) * 128 + row0) * 128 + colb;
    const unsigned int* mu32 = (const unsigned int*)msk;

    float s0 = 0.f, s1 = 0.f, s2 = 0.f, s3 = 0.f, s4 = 0.f, s5 = 0.f, sall = 0.f;
    for (int r = 0; r < 2; ++r) {
        const float4* row = (const float4*)(fb + r * 128);
        const unsigned int* mr = mu32 + (sub * 2 + r) * 8;
        #pragma unroll
        for (int j = 0; j < 8; ++j) {
            float4 v = row[j];
            unsigned int u = mr[j];
            unsigned int b0 = u, b1 = u >> 8, b2 = u >> 16, b3 = u >> 24;
            s0 += ((b0 >> 0) & 1) ? v.x : 0.f;  s1 += ((b0 >> 1) & 1) ? v.x : 0.f;
            s2 += ((b0 >> 2) & 1) ? v.x : 0.f;  s3 += ((b0 >> 3) & 1) ? v.x : 0.f;
            s4 += ((b0 >> 4) & 1) ? v.x : 0.f;  s5 += ((b0 >> 5) & 1) ? v.x : 0.f;
            s0 += ((b1 >> 0) & 1) ? v.y : 0.f;  s1 += ((b1 >> 1) & 1) ? v.y : 0.f;
            s2 += ((b1 >> 2) & 1) ? v.y : 0.f;  s3 += ((b1 >> 3) & 1) ? v.y : 0.f;
            s4 += ((b1 >> 4) & 1) ? v.y : 0.f;  s5 += ((b1 >> 5) & 1) ? v.y : 0.f;
            s0 += ((b2 >> 0) & 1) ? v.z : 0.f;  s1 += ((b2 >> 1) & 1) ? v.z : 0.f;
            s2 += ((b2 >> 2) & 1) ? v.z : 0.f;  s3 += ((b2 >> 3) & 1) ? v.z : 0.f;
            s4 += ((b2 >> 4) & 1) ? v.z : 0.f;  s5 += ((b2 >> 5) & 1) ? v.z : 0.f;
            s0 += ((b3 >> 0) & 1) ? v.w : 0.f;  s1 += ((b3 >> 1) & 1) ? v.w : 0.f;
            s2 += ((b3 >> 2) & 1) ? v.w : 0.f;  s3 += ((b3 >> 3) & 1) ? v.w : 0.f;
            s4 += ((b3 >> 4) & 1) ? v.w : 0.f;  s5 += ((b3 >> 5) & 1) ? v.w : 0.f;
            sall += v.x + v.y + v.z + v.w;
        }
    }
    if (sub > 0) {
        float* a = &accs[sub - 1][0][0];
        a[0 * 128 + c] = s0; a[1 * 128 + c] = s1; a[2 * 128 + c] = s2;
        a[3 * 128 + c] = s3; a[4 * 128 + c] = s4; a[5 * 128 + c] = s5;
        a[6 * 128 + c] = sall;
    }
    __syncthreads();
    if (sub == 0) {
        float* po = part + pidx * 896;
        po[0 * 128 + c] = s0 + accs[0][0][c] + accs[1][0][c] + accs[2][0][c];
        po[1 * 128 + c] = s1 + accs[0][1][c] + accs[1][1][c] + accs[2][1][c];
        po[2 * 128 + c] = s2 + accs[0][2][c] + accs[1][2][c] + accs[2][2][c];
        po[3 * 128 + c] = s3 + accs[0][3][c] + accs[1][3][c] + accs[2][3][c];
        po[4 * 128 + c] = s4 + accs[0][4][c] + accs[1][4][c] + accs[2][4][c];
        po[5 * 128 + c] = s5 + accs[0][5][c] + accs[1][5][c] + accs[2][5][c];
        po[6 * 128 + c] = sall + accs[0][6][c] + accs[1][6][c] + accs[2][6][c];
    }
}

// ---------------------------------------------------------------------------
// kernA2: combine quarters -> ctx -> LN1 -> gelu -> centersT + fused argmin
// (nearest prototype, first-index ties). 128 blocks x 512 threads.
// centersT layout: [row][128] (coalesced stores; contiguous rows for
// kernD's gather).
// ---------------------------------------------------------------------------
__global__ __launch_bounds__(512) void kernA2(
    const float* __restrict__ part, const unsigned char* __restrict__ maskb,
    const float* __restrict__ proto,
    const float* __restrict__ g1, const float* __restrict__ b1,
    float* __restrict__ centersT, int* __restrict__ nearest)
{
    __shared__ float ct[6][128];
    __shared__ int cnt[6];
    __shared__ float pl[48 * 129];     // proto, stride 129 -> 2-way banks (free)

    const int tid = threadIdx.x;
    const int p = blockIdx.x;                  // 0..127
    const int b = p >> 4, pp = p & 15, ihh = pp >> 2, iww = pp & 3;

    if (tid < 6) cnt[tid] = 0;
    for (int i = tid; i < 6144; i += 512)
        pl[(i >> 7) * 129 + (i & 127)] = proto[i];
    __syncthreads();

    // ---- counts from mask bytes (256 threads x 4 bytes, wave-reduced) ----
    if (tid < 256) {
        const unsigned char* mb = maskb + b * 16384 + ihh * 32 * 128 + iww * 32;
        int r = tid >> 3, jw = tid & 7;
        unsigned int u = *(const unsigned int*)(mb + r * 128 + jw * 4);
        #pragma unroll
        for (int k = 0; k < 6; ++k) {
            int cc = ((u >> k) & 1) + ((u >> (8 + k)) & 1) +
                     ((u >> (16 + k)) & 1) + ((u >> (24 + k)) & 1);
            #pragma unroll
            for (int m = 1; m < 64; m <<= 1) cc += __shfl_xor(cc, m, 64);
            if ((tid & 63) == 0 && cc) atomicAdd(&cnt[k], cc);
        }
    }
    __syncthreads();

    // ---- ctx closed form (768 items on 512 threads: STRIDED) ----
    const float* pb = part + (p * 4) * 896;
    for (int i = tid; i < 768; i += 512) {
        const int c = i & 127, k = i >> 7;
        float Sall = pb[6 * 128 + c] + pb[896 + 6 * 128 + c] +
                     pb[2 * 896 + 6 * 128 + c] + pb[3 * 896 + 6 * 128 + c];
        float Sk = pb[k * 128 + c] + pb[896 + k * 128 + c] +
                   pb[2 * 896 + k * 128 + c] + pb[3 * 896 + k * 128 + c];
        float Z = fmaf((float)cnt[k], E_M1, 1024.f);
        ct[k][c] = (Sall + E_M1 * Sk) / Z;
    }
    __syncthreads();

    // ---- LN over C + gelu -> centersT; fused nearest-proto argmin ----
    const int wv = tid >> 6, lane = tid & 63;
    if (wv < 6) {
        float x0 = ct[wv][lane], x1 = ct[wv][lane + 64];
        float s = x0 + x1;
        #pragma unroll
        for (int m = 1; m < 64; m <<= 1) s += __shfl_xor(s, m, 64);
        float mu = s * (1.f / 128.f);
        float d0 = x0 - mu, d1 = x1 - mu;
        float ss = d0 * d0 + d1 * d1;
        #pragma unroll
        for (int m = 1; m < 64; m <<= 1) ss += __shfl_xor(ss, m, 64);
        float inv = 1.f / sqrtf(ss * (1.f / 128.f) + 1e-6f);
        float y0 = d0 * inv * g1[lane] + b1[lane];
        float y1 = d1 * inv * g1[lane + 64] + b1[lane + 64];
        float z0 = gelu_exact(y0);
        float z1 = gelu_exact(y1);
        const int row = (b * 16 + pp) * 6 + wv;
        centersT[row * 128 + lane] = z0;           // [row][128] coalesced
        centersT[row * 128 + lane + 64] = z1;

        // argmin over 48 protos (strict < : first index wins, matches jnp)
        float best = INFINITY; int bi = 0;
        for (int k = 0; k < 48; ++k) {
            float t0 = z0 - pl[k * 129 + lane];
            float t1 = z1 - pl[k * 129 + 64 + lane];
            float sd = fmaf(t0, t0, t1 * t1);
            #pragma unroll
            for (int m = 1; m < 64; m <<= 1) sd += __shfl_xor(sd, m, 64);
            if (sd < best) { best = sd; bi = k; }
        }
        if (lane == 0) nearest[row] = bi;
    }
}

// ---------------------------------------------------------------------------
// kernD v4: closed-form momentum via ordered match list.
// p = 0.999^m p0 + sum_j OM*0.999^(m-1-j) v_ij  (weights as iterated
// products, descending j so w *= 0.999 is exact per-step). Wave 0 ballot-
// compacts the ~16 matching rows (ordered by construction); 128 threads
// then gather only those rows (contiguous 512B each). 48 blocks x 128.
// ---------------------------------------------------------------------------
__global__ __launch_bounds__(128) void kernD(
    const float* __restrict__ proto0, const int* __restrict__ nearest,
    const float* __restrict__ centersT,
    float* __restrict__ proto_new, float* __restrict__ pn2,
    float* __restrict__ out_expand, float* __restrict__ out_proto)
{
    __shared__ int nl[768];
    __shared__ int lidx[768];
    __shared__ int mcount;
    __shared__ float wred[2];
    const int k = blockIdx.x, c = threadIdx.x;
    for (int i = c; i < 768; i += 128) nl[i] = nearest[i];
    __syncthreads();

    // ---- ordered compaction of matching rows (wave 0, ballot) ----
    if (c < 64) {
        int m = 0;
        for (int w = 0; w < 12; ++w) {
            bool match = (nl[w * 64 + c] == k);
            unsigned long long bal = __ballot(match);
            int pre = __popcll(bal & ((1ULL << c) - 1ULL));
            if (match) lidx[m + pre] = w * 64 + c;
            m += __popcll(bal);
        }
        if (c == 0) mcount = m;
    }
    __syncthreads();

    // ---- weighted gather: j descending, w = 0.999^(m-1-j) iterated ----
    const float OM = (float)(1.0 - 0.999);
    const int m = mcount;
    float w = 1.f, s = 0.f;
    for (int j = m - 1; j >= 0; --j) {
        float v = centersT[lidx[j] * 128 + c];
        s = fmaf(OM * w, v, s);
        w *= 0.999f;
    }
    float p = fmaf(proto0[k * 128 + c], w, s);   // w = 0.999^m

    proto_new[k * 128 + c] = p;
    out_proto[k * 128 + c] = p;
    #pragma unroll
    for (int b = 0; b < 8; ++b) out_expand[(b * 48 + k) * 128 + c] = p;
    float sq = p * p;
    #pragma unroll
    for (int mm = 1; mm < 64; mm <<= 1) sq += __shfl_xor(sq, mm, 64);
    if ((c & 63) == 0) wred[c >> 6] = sq;
    __syncthreads();
    if (c == 0) pn2[k] = wred[0] + wred[1];
}

// ---------------------------------------------------------------------------
// kernE v5.1 (R7/R11-measured, ~51 µs): DMA fT staging + prot in LDS.
// 512 threads, 8 waves = (nh 2) x (cw 4). Wave (nh,cw): 32 n x 48 k x 32 c.
// Lane = 8 ng x 8 kg -> 4n x 6k. Per cq: 4 fT + 6 prot b128 reads feed 48
// pk_fma. Cross-cw reduce via red[4][48][66] (aliases dead fT+prot).
// grid (256,8) x 512. LDS 64000 B -> 2 blocks/CU, 16 waves/CU.
// ---------------------------------------------------------------------------
__global__ __launch_bounds__(512) void kernE(
    const float* __restrict__ feats, const float* __restrict__ proto_new,
    const float* __restrict__ pn2g,
    const float* __restrict__ g2, const float* __restrict__ b2,
    float* __restrict__ out_sim, float* __restrict__ out_dist,
    float* __restrict__ pred_small)
{
    __shared__ float smem[16000];
    float* fT   = smem;            // [128][64]   (dead after main loop)
    float* prot = smem + 8192;     // [48][132]   (dead after main loop)
    float* p4   = smem + 14528;    // [8][64]  F2 partials (F2 phase only)
    float* red  = smem;            // [4][48][66] (after main loop)
    float* dst  = smem + 12672;    // [64][49]    (combine phase on)
    float* lnA  = smem;            // [4][64]  LN partials (red dead by then)
    float* lnB  = smem + 256;      // [4][64]
    float* F2   = smem + 15808;    // [64]
    float* muv  = smem + 15872;    // [64]
    float* invv = smem + 15936;    // [64]

    const int t = threadIdx.x;
    const int b = blockIdx.y;
    const int nbase = blockIdx.x * 64;

    // ---- stage fT via 16B DMA (LDS byte off = idx*16 -> linear in lane) ----
    #pragma unroll
    for (int it = 0; it < 4; ++it) {
        int idx = it * 512 + t;              // 0..2047
        int c = idx >> 4, qd = idx & 15;
        gload16(feats + (((long long)(b * 128 + c)) << 14) + nbase + qd * 4,
                &fT[idx * 4]);
    }
    // ---- stage prot (register path; stride-132 rows are non-linear) ----
    for (int i4 = t; i4 < 1536; i4 += 512) {
        float4 v = ((const float4*)proto_new)[i4];
        *(float4*)&prot[(i4 >> 5) * 132 + (i4 & 31) * 4] = v;
    }
    __syncthreads();

    {   // F2[n] = sum_c f^2 (8 partials x 16 channels)
        int n = t & 63, cg = t >> 6;
        float s = 0.f;
        for (int c = cg * 16; c < cg * 16 + 16; ++c) { float x = fT[c * 64 + n]; s = fmaf(x, x, s); }
        p4[cg * 64 + n] = s;
    }
    __syncthreads();
    if (t < 64) {
        float s = 0.f;
        #pragma unroll
        for (int g = 0; g < 8; ++g) s += p4[g * 64 + t];
        F2[t] = s;          // read only after post-main barriers
    }

    // ---- main loop: wave (nh, cw); lane = (ng, kg) ----
    const int w = t >> 6, l = t & 63;
    const int cw = w & 3, nh = w >> 2;
    const int n0 = nh * 32 + (l & 7) * 4;   // 4 n per lane
    const int k0 = (l >> 3) * 6;            // 6 k per lane
    const int cbase = cw * 32;

    v2f acc[6][2];
    #pragma unroll
    for (int j = 0; j < 6; ++j) { acc[j][0] = splat2(0.f); acc[j][1] = splat2(0.f); }

    #pragma unroll
    for (int cq = 0; cq < 8; ++cq) {
        const int cb = cbase + cq * 4;
        v2f f[4][2];
        #pragma unroll
        for (int ch = 0; ch < 4; ++ch) {
            float4 a0 = *(const float4*)&fT[(cb + ch) * 64 + n0];
            f[ch][0] = *(v2f*)&a0.x; f[ch][1] = *(v2f*)&a0.z;
        }
        #pragma unroll
        for (int j = 0; j < 6; ++j) {
            float4 pv = *(const float4*)&prot[(k0 + j) * 132 + cb];
            v2f px = splat2(pv.x), py = splat2(pv.y), pz = splat2(pv.z), pw = splat2(pv.w);
            #pragma unroll
            for (int h = 0; h < 2; ++h) {
                acc[j][h] = __builtin_elementwise_fma(f[0][h], px,
                            __builtin_elementwise_fma(f[1][h], py,
                            __builtin_elementwise_fma(f[2][h], pz,
                            __builtin_elementwise_fma(f[3][h], pw, acc[j][h]))));
            }
        }
    }
    __syncthreads();   // fT & prot dead from here; region becomes red

    // ---- spill partials: red[cw][k][66-stride n]; nh halves disjoint ----
    #pragma unroll
    for (int j = 0; j < 6; ++j) {
        *(v2f*)&red[cw * 3168 + (k0 + j) * 66 + n0]     = acc[j][0];
        *(v2f*)&red[cw * 3168 + (k0 + j) * 66 + n0 + 2] = acc[j][1];
    }
    __syncthreads();

    // ---- combine 4 c-partials; 768 = (k, n-quad) cells on 512 threads ----
    for (int cell = t; cell < 768; cell += 512) {
        const int k = cell >> 4, n4 = (cell & 15) * 4;
        v2f lo = splat2(0.f), hi = splat2(0.f);
        #pragma unroll
        for (int ww = 0; ww < 4; ++ww) {
            lo += *(const v2f*)&red[ww * 3168 + k * 66 + n4];
            hi += *(const v2f*)&red[ww * 3168 + k * 66 + n4 + 2];
        }
        float pk = pn2g[k];
        float d0 = sqrtf(fmaxf(F2[n4 + 0] + pk - 2.f * lo.x, 0.f));
        float d1 = sqrtf(fmaxf(F2[n4 + 1] + pk - 2.f * lo.y, 0.f));
        float d2 = sqrtf(fmaxf(F2[n4 + 2] + pk - 2.f * hi.x, 0.f));
        float d3 = sqrtf(fmaxf(F2[n4 + 3] + pk - 2.f * hi.y, 0.f));
        float4 dv; dv.x = d0; dv.y = d1; dv.z = d2; dv.w = d3;
        *(float4*)(out_dist + (((long long)(b * 48 + k)) << 14) + nbase + n4) = dv;
        dst[(n4 + 0) * 49 + k] = 1.f / (1.f + 2.f * d0);
        dst[(n4 + 1) * 49 + k] = 1.f / (1.f + 2.f * d1);
        dst[(n4 + 2) * 49 + k] = 1.f / (1.f + 2.f * d2);
        dst[(n4 + 3) * 49 + k] = 1.f / (1.f + 2.f * d3);
    }
    __syncthreads();   // red dead from here; region becomes lnA/lnB

    // ---- LN stats per n: 256-thread partials, then combine ----
    if (t < 256) {
        const int n = t & 63, q = t >> 6;
        float s1 = 0.f, s2 = 0.f;
        for (int k = q * 12; k < q * 12 + 12; ++k) {
            float x = dst[n * 49 + k];
            s1 += x; s2 = fmaf(x, x, s2);
        }
        lnA[q * 64 + n] = s1;
        lnB[q * 64 + n] = s2;
    }
    __syncthreads();
    if (t < 64) {
        float s1 = ((lnA[t] + lnA[64 + t]) + lnA[128 + t]) + lnA[192 + t];
        float s2 = ((lnB[t] + lnB[64 + t]) + lnB[128 + t]) + lnB[192 + t];
        float mu = s1 * (1.f / 48.f);
        float var = fmaxf(s2 * (1.f / 48.f) - mu * mu, 0.f);
        muv[t] = mu;
        invv[t] = 1.f / sqrtf(var + 1e-6f);
    }
    __syncthreads();

    // ---- epilogue: 384 = (c6, n) items on 512 threads ----
    if (t < 384) {
        const int c6 = t >> 6, n = t & 63, ng = nbase + n;
        float mu = muv[n], inv = invv[n];
        float pm = 0.f;
        #pragma unroll
        for (int kp = 0; kp < 8; ++kp) {
            int k = kp * 6 + c6;
            float y = (dst[n * 49 + k] - mu) * inv * g2[k] + b2[k];
            float z = gelu_exact(y);
            out_sim[(((long long)(b * 48 + k)) << 14) + ng] = z;
            pm = (kp == 0) ? z : fmaxf(pm, z);
        }
        pred_small[((b * 6 + c6) << 14) + ng] = pm;
    }
}

// ---------------------------------------------------------------------------
// kernF: half-pixel bilinear x4 upsample (8,6,128,128)->(8,6,512,512)
// ---------------------------------------------------------------------------
__global__ __launch_bounds__(256) void kernF(
    const float* __restrict__ ps, float* __restrict__ pred)
{
    int idx = blockIdx.x * 256 + threadIdx.x;    // 3,145,728
    int xq = idx & 127;
    int oy = (idx >> 7) & 511;
    int bc = idx >> 16;
    int qy = oy >> 2, ry = oy & 3;
    int y0 = qy + ((ry < 2) ? -1 : 0);
    float fy = (ry == 0) ? 0.625f : (ry == 1) ? 0.875f : (ry == 2) ? 0.125f : 0.375f;
    int y0c = max(y0, 0), y1c = min(y0 + 1, 127);
    const float* base = ps + bc * 16384;
    const float* rA = base + y0c * 128;
    const float* rB = base + y1c * 128;
    int xm = max(xq - 1, 0), xp = min(xq + 1, 127);
    float a0 = rA[xm], a1 = rA[xq], a2 = rA[xp];
    float c0 = rB[xm], c1 = rB[xq], c2 = rB[xp];
    float w0 = 1.f - fy;
    float gm = w0 * a0 + fy * c0;
    float gc = w0 * a1 + fy * c1;
    float gp = w0 * a2 + fy * c2;
    float4 o;
    o.x = 0.375f * gm + 0.625f * gc;
    o.y = 0.125f * gm + 0.875f * gc;
    o.z = 0.875f * gc + 0.125f * gp;
    o.w = 0.625f * gc + 0.375f * gp;
    *(float4*)(pred + ((long long)idx << 2)) = o;
}

// ---------------------------------------------------------------------------
extern "C" void kernel_launch(void* const* d_in, const int* in_sizes, int n_in,
                              void* d_out, int out_size, void* d_ws, size_t ws_size,
                              hipStream_t stream)
{
    const float* feats = (const float*)d_in[0];
    const int* gt = (const int*)d_in[1];
    const float* proto = (const float*)d_in[2];
    const float* g1 = (const float*)d_in[3];
    const float* b1 = (const float*)d_in[4];
    const float* g2 = (const float*)d_in[5];
    const float* b2 = (const float*)d_in[6];

    float* out = (float*)d_out;
    float* pred       = out;
    float* out_expand = out + 12582912;
    float* out_sim    = out + 12632064;
    float* out_dist   = out + 18923520;
    float* out_proto  = out + 25214976;

    float* ws = (float*)d_ws;
    float* centersT   = ws + 98304;             // 98,304 (slot 0 unused)
    float* proto_new  = ws + 196608;            // 6,144
    float* pn2        = ws + 202752;            // 64
    int*   nearest    = (int*)(ws + 202816);    // 768
    float* part       = ws + 203584;            // 512*896 = 458,752
    float* pred_small = ws + 203584;            // ALIASED: kernE writes after
                                                // kernA2's last read of part
    unsigned char* maskb = (unsigned char*)(ws + 990016); // 131,072 B

    kernA1<<<512, 512, 0, stream>>>(feats, gt, maskb, part);
    kernA2<<<128, 512, 0, stream>>>(part, maskb, proto, g1, b1, centersT, nearest);
    kernD <<<48, 128, 0, stream>>>(proto, nearest, centersT, proto_new, pn2,
                                   out_expand, out_proto);
    kernE <<<dim3(256, 8), 512, 0, stream>>>(feats, proto_new, pn2, g2, b2,
                                             out_sim, out_dist, pred_small);
    kernF<<<12288, 256, 0, stream>>>(pred_small, pred);
}

// Round 16
// 235.651 us; speedup vs baseline: 1.3714x; 1.0463x over previous
//
#include <hip/hip_runtime.h>
#include <hip/hip_bf16.h>
#include <math.h>

// ---------------------------------------------------------------------------
// CLSNet forward. B=8, C=128, H=W=128, Horg=Worg=512, NC=6, KP=8, NPROTO=48,
// PH=PW=4 (patches 32x32), 128 patches, 768 center rows.
// Outputs: pred[8,6,512,512] | proto_expand[8,48,128] | p2c[8,48,128,128] |
// distance_l2[8,48,16384] | proto_new[48,128]
// gt arrives as int32.
// R15 measured 246.6 (best): kernD v4 closed-form (-35 vs chunked).
// R16 delta (ONE kernel): kernE v8 = bf16 MFMA dot. d >= ~9.5 for random
// data (no sqrt singularity); single-pass bf16 RNE error on out_sim <~0.05
// vs 0.125 tol. Same shell as v5.1 (8 waves = 2nh x 4cw, red/dst/combine/
// LN/epilogue verbatim, 64000B LDS). Staging: fn bf16 [n][136] (B^T, K-
// contiguous b128 frags) + pb bf16 [48][136]. Per wave: 5 frag b128 reads +
// 6 mfma_f32_16x16x32_bf16 (M=48/3 tiles, N=32/2 tiles, K=32=cw quarter)
// replacing 80 b128 + 384 pk_fma. Layouts per verified guide mappings.
// ---------------------------------------------------------------------------

#define E_M1 1.71828182845904523536f   // e - 1
#define INV_SQRT2 0.70710678118654752440f

typedef float v2f __attribute__((ext_vector_type(2)));
typedef __attribute__((ext_vector_type(8))) short bf16x8;
typedef __attribute__((ext_vector_type(4))) float f32x4;

__device__ __forceinline__ float gelu_exact(float x) {
    return 0.5f * x * (1.f + erff(x * INV_SQRT2));
}
__device__ __forceinline__ v2f splat2(float x) { v2f r; r.x = x; r.y = x; return r; }

__device__ __forceinline__ unsigned short f2bf(float f) {   // RNE fp32->bf16
    union { float f; unsigned u; } v; v.f = f;
    unsigned r = (v.u + 0x7FFFu + ((v.u >> 16) & 1u)) >> 16;
    return (unsigned short)r;
}
__device__ __forceinline__ float bf2f(unsigned short h) {
    union { unsigned u; float f; } v; v.u = ((unsigned)h) << 16; return v.f;
}

// ---------------------------------------------------------------------------
// kernA1 v4: fused mask-gen + per-(patch,quarter) segmented channel sums.
// 512 blocks x 512 threads. Phase 0 (t<256): scrambled one-hot 6-bit mask
// for the block's 8x32 pixel region (verbatim kern0b formula) -> LDS msk +
// global maskb (consumed by kernA2). Phase 1: gather, sub = t>>7 handles
// 2 of the 8 rows; LDS combine. part layout: part[pidx][7][128].
// ---------------------------------------------------------------------------
__global__ __launch_bounds__(512) void kernA1(
    const float* __restrict__ feats, const int* __restrict__ gt,
    unsigned char* __restrict__ maskb, float* __restrict__ part)
{
    __shared__ float accs[3][7][128];
    __shared__ unsigned char msk[256];          // [8 rows][32 cols]
    const int pidx = blockIdx.x;
    const int patch = pidx >> 2, q = pidx & 3;
    const int b = patch >> 4, pp = patch & 15, ihh = pp >> 2, iww = pp & 3;
    const int c = threadIdx.x & 127, sub = threadIdx.x >> 7;
    const int rowb = ihh * 32 + q * 8, colb = iww * 32;

    // ---- phase 0: mask bytes for this block's 256 pixels ----
    if (threadIdx.x < 256) {
        const int prow = threadIdx.x >> 5, pcol = threadIdx.x & 31;
        const int P = (rowb + prow) * 128 + colb + pcol;
        const int* gb = gt + b * 262144;
        unsigned int m = 0;
        #pragma unroll
        for (int cc = 0; cc < 6; ++cc) {
            int pos = cc * 16384 + P;
            int hp = pos / 768;
            int rem = pos - hp * 768;
            int wp = rem / 6;
            int kp = rem - wp * 6;
            int g = gb[(4 * hp) * 512 + 4 * wp];
            int lab = (g == 6) ? 0 : g;
            if (lab == kp) m |= (1u << cc);
        }
        msk[threadIdx.x] = (unsigned char)m;
        maskb[b * 16384 + P] = (unsigned char)m;
    }
    __syncthreads();

    // ---- phase 1: masked channel sums (2 rows per sub) ----
    const int row0 = rowb + sub * 2;
    const float* fb = feats + (((long long)(b * 128 + c)) * 128 + row0) * 128 + colb;
    const unsigned int* mu32 = (const unsigned int*)msk;

    float s0 = 0.f, s1 = 0.f, s2 = 0.f, s3 = 0.f, s4 = 0.f, s5 = 0.f, sall = 0.f;
    for (int r = 0; r < 2; ++r) {
        const float4* row = (const float4*)(fb + r * 128);
        const unsigned int* mr = mu32 + (sub * 2 + r) * 8;
        #pragma unroll
        for (int j = 0; j < 8; ++j) {
            float4 v = row[j];
            unsigned int u = mr[j];
            unsigned int b0 = u, b1 = u >> 8, b2 = u >> 16, b3 = u >> 24;
            s0 += ((b0 >> 0) & 1) ? v.x : 0.f;  s1 += ((b0 >> 1) & 1) ? v.x : 0.f;
            s2 += ((b0 >> 2) & 1) ? v.x : 0.f;  s3 += ((b0 >> 3) & 1) ? v.x : 0.f;
            s4 += ((b0 >> 4) & 1) ? v.x : 0.f;  s5 += ((b0 >> 5) & 1) ? v.x : 0.f;
            s0 += ((b1 >> 0) & 1) ? v.y : 0.f;  s1 += ((b1 >> 1) & 1) ? v.y : 0.f;
            s2 += ((b1 >> 2) & 1) ? v.y : 0.f;  s3 += ((b1 >> 3) & 1) ? v.y : 0.f;
            s4 += ((b1 >> 4) & 1) ? v.y : 0.f;  s5 += ((b1 >> 5) & 1) ? v.y : 0.f;
            s0 += ((b2 >> 0) & 1) ? v.z : 0.f;  s1 += ((b2 >> 1) & 1) ? v.z : 0.f;
            s2 += ((b2 >> 2) & 1) ? v.z : 0.f;  s3 += ((b2 >> 3) & 1) ? v.z : 0.f;
            s4 += ((b2 >> 4) & 1) ? v.z : 0.f;  s5 += ((b2 >> 5) & 1) ? v.z : 0.f;
            s0 += ((b3 >> 0) & 1) ? v.w : 0.f;  s1 += ((b3 >> 1) & 1) ? v.w : 0.f;
            s2 += ((b3 >> 2) & 1) ? v.w : 0.f;  s3 += ((b3 >> 3) & 1) ? v.w : 0.f;
            s4 += ((b3 >> 4) & 1) ? v.w : 0.f;  s5 += ((b3 >> 5) & 1) ? v.w : 0.f;
            sall += v.x + v.y + v.z + v.w;
        }
    }
    if (sub > 0) {
        float* a = &accs[sub - 1][0][0];
        a[0 * 128 + c] = s0; a[1 * 128 + c] = s1; a[2 * 128 + c] = s2;
        a[3 * 128 + c] = s3; a[4 * 128 + c] = s4; a[5 * 128 + c] = s5;
        a[6 * 128 + c] = sall;
    }
    __syncthreads();
    if (sub == 0) {
        float* po = part + pidx * 896;
        po[0 * 128 + c] = s0 + accs[0][0][c] + accs[1][0][c] + accs[2][0][c];
        po[1 * 128 + c] = s1 + accs[0][1][c] + accs[1][1][c] + accs[2][1][c];
        po[2 * 128 + c] = s2 + accs[0][2][c] + accs[1][2][c] + accs[2][2][c];
        po[3 * 128 + c] = s3 + accs[0][3][c] + accs[1][3][c] + accs[2][3][c];
        po[4 * 128 + c] = s4 + accs[0][4][c] + accs[1][4][c] + accs[2][4][c];
        po[5 * 128 + c] = s5 + accs[0][5][c] + accs[1][5][c] + accs[2][5][c];
        po[6 * 128 + c] = sall + accs[0][6][c] + accs[1][6][c] + accs[2][6][c];
    }
}

// ---------------------------------------------------------------------------
// kernA2: combine quarters -> ctx -> LN1 -> gelu -> centersT + fused argmin
// (nearest prototype, first-index ties). 128 blocks x 512 threads.
// centersT layout: [row][128].
// ---------------------------------------------------------------------------
__global__ __launch_bounds__(512) void kernA2(
    const float* __restrict__ part, const unsigned char* __restrict__ maskb,
    const float* __restrict__ proto,
    const float* __restrict__ g1, const float* __restrict__ b1,
    float* __restrict__ centersT, int* __restrict__ nearest)
{
    __shared__ float ct[6][128];
    __shared__ int cnt[6];
    __shared__ float pl[48 * 129];     // proto, stride 129 -> 2-way banks (free)

    const int tid = threadIdx.x;
    const int p = blockIdx.x;                  // 0..127
    const int b = p >> 4, pp = p & 15, ihh = pp >> 2, iww = pp & 3;

    if (tid < 6) cnt[tid] = 0;
    for (int i = tid; i < 6144; i += 512)
        pl[(i >> 7) * 129 + (i & 127)] = proto[i];
    __syncthreads();

    // ---- counts from mask bytes (256 threads x 4 bytes, wave-reduced) ----
    if (tid < 256) {
        const unsigned char* mb = maskb + b * 16384 + ihh * 32 * 128 + iww * 32;
        int r = tid >> 3, jw = tid & 7;
        unsigned int u = *(const unsigned int*)(mb + r * 128 + jw * 4);
        #pragma unroll
        for (int k = 0; k < 6; ++k) {
            int cc = ((u >> k) & 1) + ((u >> (8 + k)) & 1) +
                     ((u >> (16 + k)) & 1) + ((u >> (24 + k)) & 1);
            #pragma unroll
            for (int m = 1; m < 64; m <<= 1) cc += __shfl_xor(cc, m, 64);
            if ((tid & 63) == 0 && cc) atomicAdd(&cnt[k], cc);
        }
    }
    __syncthreads();

    // ---- ctx closed form (768 items on 512 threads: STRIDED) ----
    const float* pb = part + (p * 4) * 896;
    for (int i = tid; i < 768; i += 512) {
        const int c = i & 127, k = i >> 7;
        float Sall = pb[6 * 128 + c] + pb[896 + 6 * 128 + c] +
                     pb[2 * 896 + 6 * 128 + c] + pb[3 * 896 + 6 * 128 + c];
        float Sk = pb[k * 128 + c] + pb[896 + k * 128 + c] +
                   pb[2 * 896 + k * 128 + c] + pb[3 * 896 + k * 128 + c];
        float Z = fmaf((float)cnt[k], E_M1, 1024.f);
        ct[k][c] = (Sall + E_M1 * Sk) / Z;
    }
    __syncthreads();

    // ---- LN over C + gelu -> centersT; fused nearest-proto argmin ----
    const int wv = tid >> 6, lane = tid & 63;
    if (wv < 6) {
        float x0 = ct[wv][lane], x1 = ct[wv][lane + 64];
        float s = x0 + x1;
        #pragma unroll
        for (int m = 1; m < 64; m <<= 1) s += __shfl_xor(s, m, 64);
        float mu = s * (1.f / 128.f);
        float d0 = x0 - mu, d1 = x1 - mu;
        float ss = d0 * d0 + d1 * d1;
        #pragma unroll
        for (int m = 1; m < 64; m <<= 1) ss += __shfl_xor(ss, m, 64);
        float inv = 1.f / sqrtf(ss * (1.f / 128.f) + 1e-6f);
        float y0 = d0 * inv * g1[lane] + b1[lane];
        float y1 = d1 * inv * g1[lane + 64] + b1[lane + 64];
        float z0 = gelu_exact(y0);
        float z1 = gelu_exact(y1);
        const int row = (b * 16 + pp) * 6 + wv;
        centersT[row * 128 + lane] = z0;           // [row][128] coalesced
        centersT[row * 128 + lane + 64] = z1;

        // argmin over 48 protos (strict < : first index wins, matches jnp)
        float best = INFINITY; int bi = 0;
        for (int k = 0; k < 48; ++k) {
            float t0 = z0 - pl[k * 129 + lane];
            float t1 = z1 - pl[k * 129 + 64 + lane];
            float sd = fmaf(t0, t0, t1 * t1);
            #pragma unroll
            for (int m = 1; m < 64; m <<= 1) sd += __shfl_xor(sd, m, 64);
            if (sd < best) { best = sd; bi = k; }
        }
        if (lane == 0) nearest[row] = bi;
    }
}

// ---------------------------------------------------------------------------
// kernD v4: closed-form momentum via ordered match list.
// p = 0.999^m p0 + sum_j OM*0.999^(m-1-j) v_ij. Ballot-compacted ordered
// match list (~16 rows/k avg); gather only matching rows. 48 blocks x 128.
// ---------------------------------------------------------------------------
__global__ __launch_bounds__(128) void kernD(
    const float* __restrict__ proto0, const int* __restrict__ nearest,
    const float* __restrict__ centersT,
    float* __restrict__ proto_new, float* __restrict__ pn2,
    float* __restrict__ out_expand, float* __restrict__ out_proto)
{
    __shared__ int nl[768];
    __shared__ int lidx[768];
    __shared__ int mcount;
    __shared__ float wred[2];
    const int k = blockIdx.x, c = threadIdx.x;
    for (int i = c; i < 768; i += 128) nl[i] = nearest[i];
    __syncthreads();

    // ---- ordered compaction of matching rows (wave 0, ballot) ----
    if (c < 64) {
        int m = 0;
        for (int w = 0; w < 12; ++w) {
            bool match = (nl[w * 64 + c] == k);
            unsigned long long bal = __ballot(match);
            int pre = __popcll(bal & ((1ULL << c) - 1ULL));
            if (match) lidx[m + pre] = w * 64 + c;
            m += __popcll(bal);
        }
        if (c == 0) mcount = m;
    }
    __syncthreads();

    // ---- weighted gather: j descending, w = 0.999^(m-1-j) iterated ----
    const float OM = (float)(1.0 - 0.999);
    const int m = mcount;
    float w = 1.f, s = 0.f;
    for (int j = m - 1; j >= 0; --j) {
        float v = centersT[lidx[j] * 128 + c];
        s = fmaf(OM * w, v, s);
        w *= 0.999f;
    }
    float p = fmaf(proto0[k * 128 + c], w, s);   // w = 0.999^m

    proto_new[k * 128 + c] = p;
    out_proto[k * 128 + c] = p;
    #pragma unroll
    for (int b = 0; b < 8; ++b) out_expand[(b * 48 + k) * 128 + c] = p;
    float sq = p * p;
    #pragma unroll
    for (int mm = 1; mm < 64; mm <<= 1) sq += __shfl_xor(sq, mm, 64);
    if ((c & 63) == 0) wred[c >> 6] = sq;
    __syncthreads();
    if (c == 0) pn2[k] = wred[0] + wred[1];
}

// ---------------------------------------------------------------------------
// kernE v8: bf16 MFMA dot. 512 threads, 8 waves = (nh 2) x (cw 4). Wave:
// D tiles m={0,1,2} x n={nh*2, nh*2+1}, K-slice cw*32 (one 16x16x32 step).
// fn bf16 [64][136] (=B^T, K-contiguous), pb bf16 [48][136]. Fragments:
// lane l: row = tile*16 + (l&15), k = kslice + (l>>4)*8 .. +7 (b128).
// D: row(M=k-proto) = (l>>4)*4+reg, col(N=n) = l&15. Spill -> red[4][48][66],
// combine/LN/epilogue verbatim v5.1. LDS 64000 B -> 2 blocks/CU.
// ---------------------------------------------------------------------------
__global__ __launch_bounds__(512) void kernE(
    const float* __restrict__ feats, const float* __restrict__ proto_new,
    const float* __restrict__ pn2g,
    const float* __restrict__ g2, const float* __restrict__ b2,
    float* __restrict__ out_sim, float* __restrict__ out_dist,
    float* __restrict__ pred_small)
{
    __shared__ float smem[16000];
    unsigned short* fnS = (unsigned short*)smem;          // [64][136] bf16
    unsigned short* pbS = (unsigned short*)(smem + 4352); // [48][136] bf16
    float* red  = smem;            // [4][48][66] (after main loop)
    float* dst  = smem + 12672;    // [64][49]
    float* p4   = smem + 14528;    // [8][64]  F2 partials
    float* F2   = smem + 15808;    // [64]
    float* muv  = smem + 15872;    // [64]
    float* invv = smem + 15936;    // [64]
    float* lnA  = smem;            // [4][64] (red dead by LN phase)
    float* lnB  = smem + 256;      // [4][64]

    const int t = threadIdx.x;
    const int b = blockIdx.y;
    const int nbase = blockIdx.x * 64;

    // ---- stage fn: bf16 transposed [n][136] from feats (n-contig reads) ----
    #pragma unroll
    for (int it = 0; it < 4; ++it) {
        int idx = it * 512 + t;              // 0..2047
        int c = idx >> 4, n0 = (idx & 15) * 4;
        float4 v = *(const float4*)(feats + (((long long)(b * 128 + c)) << 14) + nbase + n0);
        fnS[(n0 + 0) * 136 + c] = f2bf(v.x);
        fnS[(n0 + 1) * 136 + c] = f2bf(v.y);
        fnS[(n0 + 2) * 136 + c] = f2bf(v.z);
        fnS[(n0 + 3) * 136 + c] = f2bf(v.w);
    }
    // ---- stage pb: bf16 [48][136] from proto_new ----
    #pragma unroll
    for (int it = 0; it < 3; ++it) {
        int i4 = it * 512 + t;               // 0..1535
        int row = i4 >> 5, col4 = (i4 & 31) * 4;
        float4 v = ((const float4*)proto_new)[i4];
        ushort4 h;
        h.x = f2bf(v.x); h.y = f2bf(v.y); h.z = f2bf(v.z); h.w = f2bf(v.w);
        *(ushort4*)&pbS[row * 136 + col4] = h;
    }
    __syncthreads();

    {   // F2[n] = sum_c f^2 from bf16 fn (8 partials x 16 channels)
        int n = t & 63, cg = t >> 6;
        const unsigned short* r = &fnS[n * 136 + cg * 16];
        float s = 0.f;
        #pragma unroll
        for (int j = 0; j < 16; ++j) { float x = bf2f(r[j]); s = fmaf(x, x, s); }
        p4[cg * 64 + n] = s;
    }
    __syncthreads();
    if (t < 64) {
        float s = 0.f;
        #pragma unroll
        for (int g = 0; g < 8; ++g) s += p4[g * 64 + t];
        F2[t] = s;          // read only after post-main barriers
    }

    // ---- main: wave (nh, cw); 5 frag loads + 6 MFMA ----
    const int w = t >> 6, l = t & 63;
    const int cw = w & 3, nh = w >> 2;
    const int lr = l & 15;
    const int kb = cw * 32 + (l >> 4) * 8;   // this lane's 8-k start

    bf16x8 af0 = *(const bf16x8*)&pbS[(0 + lr) * 136 + kb];
    bf16x8 af1 = *(const bf16x8*)&pbS[(16 + lr) * 136 + kb];
    bf16x8 af2 = *(const bf16x8*)&pbS[(32 + lr) * 136 + kb];
    bf16x8 bg0 = *(const bf16x8*)&fnS[(nh * 32 + lr) * 136 + kb];
    bf16x8 bg1 = *(const bf16x8*)&fnS[(nh * 32 + 16 + lr) * 136 + kb];

    f32x4 acc00 = {0.f, 0.f, 0.f, 0.f}, acc01 = acc00;
    f32x4 acc10 = acc00, acc11 = acc00, acc20 = acc00, acc21 = acc00;
    acc00 = __builtin_amdgcn_mfma_f32_16x16x32_bf16(af0, bg0, acc00, 0, 0, 0);
    acc01 = __builtin_amdgcn_mfma_f32_16x16x32_bf16(af0, bg1, acc01, 0, 0, 0);
    acc10 = __builtin_amdgcn_mfma_f32_16x16x32_bf16(af1, bg0, acc10, 0, 0, 0);
    acc11 = __builtin_amdgcn_mfma_f32_16x16x32_bf16(af1, bg1, acc11, 0, 0, 0);
    acc20 = __builtin_amdgcn_mfma_f32_16x16x32_bf16(af2, bg0, acc20, 0, 0, 0);
    acc21 = __builtin_amdgcn_mfma_f32_16x16x32_bf16(af2, bg1, acc21, 0, 0, 0);
    __syncthreads();   // fn & pb dead from here; region becomes red

    // ---- spill D to red[cw][k][66-stride n] (D row=(l>>4)*4+r, col=l&15) ----
    {
        const int kr = (l >> 4) * 4;           // D row base within tile
        const int n0 = nh * 32 + lr;           // n for col tile 0
        const int n1 = nh * 32 + 16 + lr;      // n for col tile 1
        #pragma unroll
        for (int r = 0; r < 4; ++r) {
            red[cw * 3168 + (kr + r) * 66 + n0]        = acc00[r];
            red[cw * 3168 + (kr + r) * 66 + n1]        = acc01[r];
            red[cw * 3168 + (16 + kr + r) * 66 + n0]   = acc10[r];
            red[cw * 3168 + (16 + kr + r) * 66 + n1]   = acc11[r];
            red[cw * 3168 + (32 + kr + r) * 66 + n0]   = acc20[r];
            red[cw * 3168 + (32 + kr + r) * 66 + n1]   = acc21[r];
        }
    }
    __syncthreads();

    // ---- combine 4 c-partials; 768 = (k, n-quad) cells on 512 threads ----
    for (int cell = t; cell < 768; cell += 512) {
        const int k = cell >> 4, n4 = (cell & 15) * 4;
        v2f lo = splat2(0.f), hi = splat2(0.f);
        #pragma unroll
        for (int ww = 0; ww < 4; ++ww) {
            lo += *(const v2f*)&red[ww * 3168 + k * 66 + n4];
            hi += *(const v2f*)&red[ww * 3168 + k * 66 + n4 + 2];
        }
        float pk = pn2g[k];
        float d0 = sqrtf(fmaxf(F2[n4 + 0] + pk - 2.f * lo.x, 0.f));
        float d1 = sqrtf(fmaxf(F2[n4 + 1] + pk - 2.f * lo.y, 0.f));
        float d2 = sqrtf(fmaxf(F2[n4 + 2] + pk - 2.f * hi.x, 0.f));
        float d3 = sqrtf(fmaxf(F2[n4 + 3] + pk - 2.f * hi.y, 0.f));
        float4 dv; dv.x = d0; dv.y = d1; dv.z = d2; dv.w = d3;
        *(float4*)(out_dist + (((long long)(b * 48 + k)) << 14) + nbase + n4) = dv;
        dst[(n4 + 0) * 49 + k] = 1.f / (1.f + 2.f * d0);
        dst[(n4 + 1) * 49 + k] = 1.f / (1.f + 2.f * d1);
        dst[(n4 + 2) * 49 + k] = 1.f / (1.f + 2.f * d2);
        dst[(n4 + 3) * 49 + k] = 1.f / (1.f + 2.f * d3);
    }
    __syncthreads();   // red dead from here; region becomes lnA/lnB

    // ---- LN stats per n: 256-thread partials, then combine ----
    if (t < 256) {
        const int n = t & 63, q = t >> 6;
        float s1 = 0.f, s2 = 0.f;
        for (int k = q * 12; k < q * 12 + 12; ++k) {
            float x = dst[n * 49 + k];
            s1 += x; s2 = fmaf(x, x, s2);
        }
        lnA[q * 64 + n] = s1;
        lnB[q * 64 + n] = s2;
    }
    __syncthreads();
    if (t < 64) {
        float s1 = ((lnA[t] + lnA[64 + t]) + lnA[128 + t]) + lnA[192 + t];
        float s2 = ((lnB[t] + lnB[64 + t]) + lnB[128 + t]) + lnB[192 + t];
        float mu = s1 * (1.f / 48.f);
        float var = fmaxf(s2 * (1.f / 48.f) - mu * mu, 0.f);
        muv[t] = mu;
        invv[t] = 1.f / sqrtf(var + 1e-6f);
    }
    __syncthreads();

    // ---- epilogue: 384 = (c6, n) items on 512 threads ----
    if (t < 384) {
        const int c6 = t >> 6, n = t & 63, ng = nbase + n;
        float mu = muv[n], inv = invv[n];
        float pm = 0.f;
        #pragma unroll
        for (int kp = 0; kp < 8; ++kp) {
            int k = kp * 6 + c6;
            float y = (dst[n * 49 + k] - mu) * inv * g2[k] + b2[k];
            float z = gelu_exact(y);
            out_sim[(((long long)(b * 48 + k)) << 14) + ng] = z;
            pm = (kp == 0) ? z : fmaxf(pm, z);
        }
        pred_small[((b * 6 + c6) << 14) + ng] = pm;
    }
}

// ---------------------------------------------------------------------------
// kernF: half-pixel bilinear x4 upsample (8,6,128,128)->(8,6,512,512)
// ---------------------------------------------------------------------------
__global__ __launch_bounds__(256) void kernF(
    const float* __restrict__ ps, float* __restrict__ pred)
{
    int idx = blockIdx.x * 256 + threadIdx.x;    // 3,145,728
    int xq = idx & 127;
    int oy = (idx >> 7) & 511;
    int bc = idx >> 16;
    int qy = oy >> 2, ry = oy & 3;
    int y0 = qy + ((ry < 2) ? -1 : 0);
    float fy = (ry == 0) ? 0.625f : (ry == 1) ? 0.875f : (ry == 2) ? 0.125f : 0.375f;
    int y0c = max(y0, 0), y1c = min(y0 + 1, 127);
    const float* base = ps + bc * 16384;
    const float* rA = base + y0c * 128;
    const float* rB = base + y1c * 128;
    int xm = max(xq - 1, 0), xp = min(xq + 1, 127);
    float a0 = rA[xm], a1 = rA[xq], a2 = rA[xp];
    float c0 = rB[xm], c1 = rB[xq], c2 = rB[xp];
    float w0 = 1.f - fy;
    float gm = w0 * a0 + fy * c0;
    float gc = w0 * a1 + fy * c1;
    float gp = w0 * a2 + fy * c2;
    float4 o;
    o.x = 0.375f * gm + 0.625f * gc;
    o.y = 0.125f * gm + 0.875f * gc;
    o.z = 0.875f * gc + 0.125f * gp;
    o.w = 0.625f * gc + 0.375f * gp;
    *(float4*)(pred + ((long long)idx << 2)) = o;
}

// ---------------------------------------------------------------------------
extern "C" void kernel_launch(void* const* d_in, const int* in_sizes, int n_in,
                              void* d_out, int out_size, void* d_ws, size_t ws_size,
                              hipStream_t stream)
{
    const float* feats = (const float*)d_in[0];
    const int* gt = (const int*)d_in[1];
    const float* proto = (const float*)d_in[2];
    const float* g1 = (const float*)d_in[3];
    const float* b1 = (const float*)d_in[4];
    const float* g2 = (const float*)d_in[5];
    const float* b2 = (const float*)d_in[6];

    float* out = (float*)d_out;
    float* pred       = out;
    float* out_expand = out + 12582912;
    float* out_sim    = out + 12632064;
    float* out_dist   = out + 18923520;
    float* out_proto  = out + 25214976;

    float* ws = (float*)d_ws;
    float* centersT   = ws + 98304;             // 98,304 (slot 0 unused)
    float* proto_new  = ws + 196608;            // 6,144
    float* pn2        = ws + 202752;            // 64
    int*   nearest    = (int*)(ws + 202816);    // 768
    float* part       = ws + 203584;            // 512*896 = 458,752
    float* pred_small = ws + 203584;            // ALIASED: kernE writes after
                                                // kernA2's last read of part
    unsigned char* maskb = (unsigned char*)(ws + 990016); // 131,072 B

    kernA1<<<512, 512, 0, stream>>>(feats, gt, maskb, part);
    kernA2<<<128, 512, 0, stream>>>(part, maskb, proto, g1, b1, centersT, nearest);
    kernD <<<48, 128, 0, stream>>>(proto, nearest, centersT, proto_new, pn2,
                                   out_expand, out_proto);
    kernE <<<dim3(256, 8), 512, 0, stream>>>(feats, proto_new, pn2, g2, b2,
                                             out_sim, out_dist, pred_small);
    kernF<<<12288, 256, 0, stream>>>(pred_small, pred);
}